// Round 12
// baseline (101.052 us; speedup 1.0000x reference)
//
#include <hip/hip_runtime.h>
#include <hip/hip_bf16.h>

// SelfAttentionBlock: B=4, C=256, RC=128, H=W=64 (N=4096)
// Round 12: round-11 fused structure + T14 on the epilogue: the x-residual
// loads (16 f32/lane), bo and gamma are issued right after the main loop,
// so their HBM latency hides under the 8-way merge + Wo GEMM.
// k_qkv and the k_attn main loop are unchanged (verified round 10/11).

#define B_   4
#define C_   256
#define RC_  128
#define N_   4096
#define SCALEL 0.12750880597462906f                // (1/sqrt(128)) * log2(e)

typedef __bf16 bf16x8 __attribute__((ext_vector_type(8)));
typedef unsigned short u16x8 __attribute__((ext_vector_type(8)));
typedef float f32x4 __attribute__((ext_vector_type(4)));

static __device__ __forceinline__ unsigned short f2bf(float f) {
    unsigned int u = __builtin_bit_cast(unsigned int, f);
    u += 0x7fffu + ((u >> 16) & 1u);
    return (unsigned short)(u >> 16);
}

static __device__ __forceinline__ f32x4 mfma16(u16x8 a, u16x8 b, f32x4 c) {
    return __builtin_amdgcn_mfma_f32_16x16x32_bf16(
        __builtin_bit_cast(bf16x8, a), __builtin_bit_cast(bf16x8, b), c, 0, 0, 0);
}

static __device__ __forceinline__ unsigned int cvtpk(float lo, float hi) {
    unsigned int r;
    asm("v_cvt_pk_bf16_f32 %0, %1, %2" : "=v"(r) : "v"(lo), "v"(hi));
    return r;   // low 16 = bf16(lo), high 16 = bf16(hi), RNE
}

// load 8 consecutive f32 weights and pack to bf16x8 (same RNE as f2bf)
static __device__ __forceinline__ u16x8 ldw8(const float* p) {
    float4 f0 = *(const float4*)p;
    float4 f1 = *(const float4*)(p + 4);
    int4 pk;
    pk.x = (int)cvtpk(f0.x, f0.y);
    pk.y = (int)cvtpk(f0.z, f0.w);
    pk.z = (int)cvtpk(f1.x, f1.y);
    pk.w = (int)cvtpk(f1.z, f1.w);
    return __builtin_bit_cast(u16x8, pk);
}

static __device__ __forceinline__ void gl_lds16(const void* g, void* l) {
    __builtin_amdgcn_global_load_lds(
        (const __attribute__((address_space(1))) void*)g,
        (__attribute__((address_space(3))) void*)l, 16, 0, 0);
}

// ---------------- kernel 1: QKV projection (round-10 verified) ----------------
#define K1_LDA 264  // 256 + 8 pad (shorts)

__global__ __launch_bounds__(256) void k_qkv(
    const float* __restrict__ x,
    const float* __restrict__ wq, const float* __restrict__ wk, const float* __restrict__ wv,
    const float* __restrict__ bq, const float* __restrict__ bk, const float* __restrict__ bv,
    unsigned short* __restrict__ Qb, unsigned short* __restrict__ Kb,
    unsigned short* __restrict__ Vt)
{
    __shared__ unsigned short lds[32 * K1_LDA];   // 16.9 KB
    const int b  = blockIdx.y;
    const int n0 = blockIdx.x * 32;
    const int t  = threadIdx.x;
    const int lane = t & 63, wv_ = t >> 6;
    const int g = lane >> 4, q16 = lane & 15;

    // stage x[b][c][n0+tok] -> lds[tok][c]
    {
        int tok = t & 31;
        int cb  = (t >> 5) * 32;
        const float* xb = x + ((size_t)b * C_ * N_) + n0 + tok;
        #pragma unroll
        for (int it = 0; it < 4; ++it) {
            int c0 = cb + it * 8;
            u16x8 v;
            #pragma unroll
            for (int e = 0; e < 8; ++e)
                v[e] = f2bf(xb[(size_t)(c0 + e) * N_]);
            *(u16x8*)&lds[tok * K1_LDA + c0] = v;
        }
    }
    __syncthreads();

    f32x4 acc[3][2][2];   // [tq][r2][nf]
    #pragma unroll
    for (int tq = 0; tq < 3; ++tq)
        #pragma unroll
        for (int r2 = 0; r2 < 2; ++r2)
            #pragma unroll
            for (int nf = 0; nf < 2; ++nf)
                acc[tq][r2][nf] = (f32x4){0.f, 0.f, 0.f, 0.f};

    const float* wsrc[3] = {wq, wk, wv};
    const int rbase = wv_ * 32;
    #pragma unroll
    for (int ks = 0; ks < 8; ++ks) {
        u16x8 a[2];
        #pragma unroll
        for (int nf = 0; nf < 2; ++nf)
            a[nf] = *(const u16x8*)&lds[(nf * 16 + q16) * K1_LDA + ks * 32 + g * 8];
        #pragma unroll
        for (int tq = 0; tq < 3; ++tq) {
            const float* w = wsrc[tq];
            #pragma unroll
            for (int r2 = 0; r2 < 2; ++r2) {
                u16x8 bf = ldw8(&w[(size_t)(rbase + r2 * 16 + q16) * 256 + ks * 32 + g * 8]);
                #pragma unroll
                for (int nf = 0; nf < 2; ++nf)
                    acc[tq][r2][nf] = mfma16(a[nf], bf, acc[tq][r2][nf]);
            }
        }
    }

    #pragma unroll
    for (int r2 = 0; r2 < 2; ++r2) {
        int r = rbase + r2 * 16 + q16;
        float biasq = bq[r], biask = bk[r];
        #pragma unroll
        for (int nf = 0; nf < 2; ++nf) {
            #pragma unroll
            for (int i = 0; i < 4; ++i) {
                int n = n0 + nf * 16 + g * 4 + i;
                size_t idx = ((size_t)b * N_ + n) * RC_ + r;
                Qb[idx] = f2bf((acc[0][r2][nf][i] + biasq) * SCALEL);
                Kb[idx] = f2bf(acc[1][r2][nf][i] + biask);
            }
        }
    }

    // V direct store in image layout (stride 36 shorts); this block = one key-tile.
    const size_t tile = (size_t)b * 128 + blockIdx.x;
    #pragma unroll
    for (int r2 = 0; r2 < 2; ++r2) {
        int r = rbase + r2 * 16 + q16;
        float biasv = bv[r];
        #pragma unroll
        for (int nf = 0; nf < 2; ++nf) {
            unsigned int w0 = (unsigned int)f2bf(acc[2][r2][nf][0] + biasv)
                            | ((unsigned int)f2bf(acc[2][r2][nf][1] + biasv) << 16);
            unsigned int w1 = (unsigned int)f2bf(acc[2][r2][nf][2] + biasv)
                            | ((unsigned int)f2bf(acc[2][r2][nf][3] + biasv) << 16);
            unsigned short* dst = Vt + (tile * 128 + r) * 36 + g * 8 + nf * 4;
            *(uint2*)dst = make_uint2(w0, w1);
        }
    }
}

// ---------------- kernel 2: flash attention + fused output projection ----------------
// 16 waves: qw = wv&1 (32 q-rows), grp = wv>>1 (512 keys, 16 tiles of 32).
// smem (shorts): Q [0,8192) 64x128 XOR-swz; K @8192+grp*4096: [32][128] XOR-swz (DMA);
//                V @40960+grp*4608: [128][36] image (linear DMA copy).
// merge overlay: l f32 @ [0,1024); U bf16 8x[64][132] @ [8192, 75776).
// fused-out overlay: Ol bf16 [64][136] @ [8192, 16896).
#define QS 136

__global__ __launch_bounds__(1024, 4) void k_attn(
    const unsigned short* __restrict__ Qb, const unsigned short* __restrict__ Kb,
    const unsigned short* __restrict__ Vt,
    const float* __restrict__ wo, const float* __restrict__ bo,
    const float* __restrict__ x, const float* __restrict__ gamma,
    float* __restrict__ out)
{
    __shared__ __align__(16) unsigned short smem[77824];   // 152 KiB
    const int b  = blockIdx.y;
    const int n0 = blockIdx.x * 64;
    const int t  = threadIdx.x;
    const int lane = t & 63, wv_ = t >> 6;        // 16 waves
    const int qw = wv_ & 1, grp = wv_ >> 1;       // 8 KV groups
    const int g = lane >> 4, q16 = lane & 15;

    unsigned short* Ql = smem;
    unsigned short* Kl = smem + 8192 + grp * 4096;
    unsigned short* Vl = smem + 40960 + grp * 4608;

    const unsigned short* Qg = Qb + ((size_t)b * N_ + n0) * RC_;
    const unsigned short* Kg = Kb + ((size_t)b * N_ + grp * 512) * RC_;
    const unsigned short* Vg = Vt + ((size_t)b * 128 + grp * 16) * 4608;

    // ---- Q stage: register path + XOR-swizzled ds_write ----
    {
        int sq = wv_ * 64 + lane;                 // 0..1023
        int row = sq >> 4, ch = sq & 15;
        uint4 v = *(const uint4*)&Qg[(size_t)row * RC_ + ch * 8];
        *(uint4*)&Ql[row * 128 + ((ch ^ (row & 7)) * 8)] = v;
    }

    // ---- DMA staging: wave-uniform LDS dest + per-lane (pre-swizzled) source ----
    #define STAGEK(kt_) do { int ktc = (kt_);                                    \
        _Pragma("unroll")                                                        \
        for (int r = 0; r < 4; ++r) {                                            \
            int m = qw * 4 + r;                                                  \
            int row = m * 4 + (lane >> 4);                                       \
            int ch = (lane & 15) ^ (row & 7);                                    \
            gl_lds16(Kg + (size_t)(ktc * 32 + row) * RC_ + ch * 8,               \
                     (char*)Kl + m * 1024);                                      \
        }                                                                        \
    } while (0)
    #define STAGEV(kt_) do { int ktc = (kt_);                                    \
        const char* vsrc = (const char*)(Vg + (size_t)ktc * 4608);               \
        char* vdst = (char*)Vl;                                                  \
        _Pragma("unroll")                                                        \
        for (int j = 0; j < 4; ++j) {                                            \
            int off = j * 2048 + qw * 1024;                                      \
            gl_lds16(vsrc + off + lane * 16, vdst + off);                        \
        }                                                                        \
        if (qw == 0)                                                             \
            gl_lds16(vsrc + 8192 + lane * 16, vdst + 8192);                      \
    } while (0)

    STAGEK(0);
    STAGEV(0);

    f32x4 acc_o[2][8];
    #pragma unroll
    for (int rf = 0; rf < 2; ++rf)
        #pragma unroll
        for (int df = 0; df < 8; ++df)
            acc_o[rf][df] = (f32x4){0.f, 0.f, 0.f, 0.f};
    float l_loc[2] = {0.f, 0.f};

    __syncthreads();   // Q ds_write + initial K/V DMA drained

    for (int kt = 0; kt < 16; ++kt) {
        // S^T = K Q^T (swapped): lane holds S[q = qblock + q16][k = kf*16 + g*4 + i]
        f32x4 s[2][2];
        #pragma unroll
        for (int rf = 0; rf < 2; ++rf)
            #pragma unroll
            for (int kf = 0; kf < 2; ++kf)
                s[rf][kf] = (f32x4){0.f, 0.f, 0.f, 0.f};
        __builtin_amdgcn_s_setprio(1);
        #pragma unroll
        for (int ks = 0; ks < 4; ++ks) {
            int sw = ((4 * ks + g) ^ (q16 & 7)) * 8;
            u16x8 qf0 = *(const u16x8*)&Ql[(qw * 32 + q16) * 128 + sw];
            u16x8 qf1 = *(const u16x8*)&Ql[(qw * 32 + 16 + q16) * 128 + sw];
            #pragma unroll
            for (int kf = 0; kf < 2; ++kf) {
                u16x8 kfr = *(const u16x8*)&Kl[(kf * 16 + q16) * 128 + sw];
                s[0][kf] = mfma16(kfr, qf0, s[0][kf]);
                s[1][kf] = mfma16(kfr, qf1, s[1][kf]);
            }
        }
        __builtin_amdgcn_s_setprio(0);

        __syncthreads();              // A: all QK reads of Kl done; V-DMA drained
        if (kt < 15) STAGEK(kt + 1);  // K-DMA flies under softmax + PV

        // no-max softmax: p = exp2(S') (log2e folded into Q); pack P via cvt_pk
        u16x8 pa[2];
        #pragma unroll
        for (int rf = 0; rf < 2; ++rf) {
            #pragma unroll
            for (int kf = 0; kf < 2; ++kf)
                #pragma unroll
                for (int i = 0; i < 4; ++i)
                    s[rf][kf][i] = exp2f(s[rf][kf][i]);
            l_loc[rf] += (s[rf][0][0] + s[rf][0][1]) + (s[rf][0][2] + s[rf][0][3])
                       + (s[rf][1][0] + s[rf][1][1]) + (s[rf][1][2] + s[rf][1][3]);
            int4 pk;
            pk.x = (int)cvtpk(s[rf][0][0], s[rf][0][1]);
            pk.y = (int)cvtpk(s[rf][0][2], s[rf][0][3]);
            pk.z = (int)cvtpk(s[rf][1][0], s[rf][1][1]);
            pk.w = (int)cvtpk(s[rf][1][2], s[rf][1][3]);
            pa[rf] = __builtin_bit_cast(u16x8, pk);
        }

        // O += P @ V.  V image row d: lane's 8 B-slots contiguous at short offset
        // g*8, read as two 8B chunks (stride 72B not 16B-aligned for odd d).
        __builtin_amdgcn_s_setprio(1);
        #pragma unroll
        for (int df = 0; df < 8; ++df) {
            int d = df * 16 + q16;
            const unsigned short* vrow = &Vl[d * 36 + g * 8];
            uint2 vlo = *(const uint2*)&vrow[0];
            uint2 vhi = *(const uint2*)&vrow[4];
            int4 vv = make_int4((int)vlo.x, (int)vlo.y, (int)vhi.x, (int)vhi.y);
            u16x8 vb = __builtin_bit_cast(u16x8, vv);
            acc_o[0][df] = mfma16(pa[0], vb, acc_o[0][df]);
            acc_o[1][df] = mfma16(pa[1], vb, acc_o[1][df]);
        }
        __builtin_amdgcn_s_setprio(0);

        __syncthreads();              // B: all PV reads of Vl done; K-DMA drained
        if (kt < 15) STAGEV(kt + 1);  // V-DMA flies under next iter's QK
    }

    // ---- T14: early-issue the epilogue's residual/bias loads; their HBM
    //      latency hides under the merge + Wo GEMM below ----
    const int cw = wv_ * 16;                        // 16 waves x 16 channels = 256
    float xr[4][4], bo_r[4];
    float gm = gamma[0];
    #pragma unroll
    for (int i = 0; i < 4; ++i) {
        int c = cw + g * 4 + i;
        bo_r[i] = bo[c];
        const float* xp = x + ((size_t)b * C_ + c) * N_ + n0 + q16;
        #pragma unroll
        for (int nf = 0; nf < 4; ++nf)
            xr[i][nf] = xp[nf * 16];
    }
    __builtin_amdgcn_sched_barrier(0);              // pin loads ahead of the merge

    // ---- merge across 8 KV groups ----
    float l0 = l_loc[0], l1 = l_loc[1];
    l0 += __shfl_xor(l0, 16); l0 += __shfl_xor(l0, 32);
    l1 += __shfl_xor(l1, 16); l1 += __shfl_xor(l1, 32);

    float* lf = (float*)smem;                       // [8 grp][64 rows]
    unsigned short* Ub = smem + 8192;               // [8 grp][64][132] bf16
    if (g == 0) {
        lf[grp * 64 + qw * 32 + q16]      = l0;
        lf[grp * 64 + qw * 32 + 16 + q16] = l1;
    }
    {
        unsigned short* Ug = Ub + grp * 8448;
        #pragma unroll
        for (int rf = 0; rf < 2; ++rf)
            #pragma unroll
            for (int df = 0; df < 8; ++df)
                #pragma unroll
                for (int i = 0; i < 4; ++i)
                    Ug[(qw * 32 + rf * 16 + g * 4 + i) * 132 + df * 16 + q16] =
                        f2bf(acc_o[rf][df][i]);
    }
    __syncthreads();

    // combine into registers: wave wv_ owns q-rows [wv_*4, wv_*4+4), lane -> 2 d-cols
    unsigned int po[4];
    #pragma unroll
    for (int r = 0; r < 4; ++r) {
        int row = wv_ * 4 + r;
        float lt = 0.f;
        #pragma unroll
        for (int gg = 0; gg < 8; ++gg) lt += lf[gg * 64 + row];
        float inv = 1.f / lt;
        float o0 = 0.f, o1 = 0.f;
        #pragma unroll
        for (int gg = 0; gg < 8; ++gg) {
            unsigned int u = *(const unsigned int*)&Ub[gg * 8448 + row * 132 + lane * 2];
            o0 += __builtin_bit_cast(float, u << 16);
            o1 += __builtin_bit_cast(float, u & 0xffff0000u);
        }
        po[r] = cvtpk(o0 * inv, o1 * inv);
    }
    __syncthreads();                  // all Ub reads done; safe to overlay Ol

    // ---- fused output projection (verified k_out pattern) ----
    unsigned short* Ol = smem + 8192;               // [64][136] bf16
    #pragma unroll
    for (int r = 0; r < 4; ++r)
        *(unsigned int*)&Ol[(wv_ * 4 + r) * QS + lane * 2] = po[r];
    __syncthreads();

    f32x4 acc[4];
    #pragma unroll
    for (int nf = 0; nf < 4; ++nf)
        acc[nf] = (f32x4){0.f, 0.f, 0.f, 0.f};

    #pragma unroll
    for (int ks = 0; ks < 4; ++ks) {
        u16x8 b8[4];
        #pragma unroll
        for (int nf = 0; nf < 4; ++nf)
            b8[nf] = *(const u16x8*)&Ol[(nf * 16 + q16) * QS + ks * 32 + g * 8];
        u16x8 a8 = ldw8(&wo[(size_t)(cw + q16) * 128 + ks * 32 + g * 8]);
        #pragma unroll
        for (int nf = 0; nf < 4; ++nf)
            acc[nf] = mfma16(a8, b8[nf], acc[nf]);
    }

    #pragma unroll
    for (int i = 0; i < 4; ++i) {
        int c = cw + g * 4 + i;
        #pragma unroll
        for (int nf = 0; nf < 4; ++nf) {
            int n = n0 + nf * 16 + q16;
            size_t idx = ((size_t)b * C_ + c) * N_ + n;
            out[idx] = gm * (acc[nf][i] + bo_r[i]) + xr[i][nf];
        }
    }
    #undef STAGEK
    #undef STAGEV
}

extern "C" void kernel_launch(void* const* d_in, const int* in_sizes, int n_in,
                              void* d_out, int out_size, void* d_ws, size_t ws_size,
                              hipStream_t stream) {
    const float* x     = (const float*)d_in[0];
    const float* wq    = (const float*)d_in[1];
    const float* bq    = (const float*)d_in[2];
    const float* wk    = (const float*)d_in[3];
    const float* bk    = (const float*)d_in[4];
    const float* wv    = (const float*)d_in[5];
    const float* bv    = (const float*)d_in[6];
    const float* wo    = (const float*)d_in[7];
    const float* bo    = (const float*)d_in[8];
    const float* gamma = (const float*)d_in[9];
    float* out = (float*)d_out;

    unsigned short* ws = (unsigned short*)d_ws;
    unsigned short* Qb = ws;                   // [B][N][RC] bf16
    unsigned short* Kb = Qb + 2097152;         // [B][N][RC] bf16
    unsigned short* Vt = Kb + 2097152;         // [B*128 tiles][128][36] image

    dim3 g1(128, 4);
    k_qkv<<<g1, 256, 0, stream>>>(x, wq, wk, wv, bq, bk, bv, Qb, Kb, Vt);
    dim3 g2(64, 4);
    k_attn<<<g2, 1024, 0, stream>>>(Qb, Kb, Vt, wo, bo, x, gamma, out);
}

// Round 13
// 98.750 us; speedup vs baseline: 1.0233x; 1.0233x over previous
//
#include <hip/hip_runtime.h>
#include <hip/hip_bf16.h>

// SelfAttentionBlock: B=4, C=256, RC=128, H=W=64 (N=4096)
// Round 13: revert to round-10 structure (best verified: 98.8us — the round
// 11/12 epilogue fusion measured worse and is abandoned). One delta vs round
// 10: k_qkv's x-staging vectorized (8x float4 loads over tokens instead of 32
// scalar f32 loads; identical LDS image, same ds_write count).

#define B_   4
#define C_   256
#define RC_  128
#define N_   4096
#define SCALEL 0.12750880597462906f                // (1/sqrt(128)) * log2(e)

typedef __bf16 bf16x8 __attribute__((ext_vector_type(8)));
typedef unsigned short u16x8 __attribute__((ext_vector_type(8)));
typedef float f32x4 __attribute__((ext_vector_type(4)));

static __device__ __forceinline__ unsigned short f2bf(float f) {
    unsigned int u = __builtin_bit_cast(unsigned int, f);
    u += 0x7fffu + ((u >> 16) & 1u);
    return (unsigned short)(u >> 16);
}

static __device__ __forceinline__ f32x4 mfma16(u16x8 a, u16x8 b, f32x4 c) {
    return __builtin_amdgcn_mfma_f32_16x16x32_bf16(
        __builtin_bit_cast(bf16x8, a), __builtin_bit_cast(bf16x8, b), c, 0, 0, 0);
}

static __device__ __forceinline__ unsigned int cvtpk(float lo, float hi) {
    unsigned int r;
    asm("v_cvt_pk_bf16_f32 %0, %1, %2" : "=v"(r) : "v"(lo), "v"(hi));
    return r;   // low 16 = bf16(lo), high 16 = bf16(hi), RNE
}

// load 8 consecutive f32 weights and pack to bf16x8 (same RNE as f2bf)
static __device__ __forceinline__ u16x8 ldw8(const float* p) {
    float4 f0 = *(const float4*)p;
    float4 f1 = *(const float4*)(p + 4);
    int4 pk;
    pk.x = (int)cvtpk(f0.x, f0.y);
    pk.y = (int)cvtpk(f0.z, f0.w);
    pk.z = (int)cvtpk(f1.x, f1.y);
    pk.w = (int)cvtpk(f1.z, f1.w);
    return __builtin_bit_cast(u16x8, pk);
}

static __device__ __forceinline__ void gl_lds16(const void* g, void* l) {
    __builtin_amdgcn_global_load_lds(
        (const __attribute__((address_space(1))) void*)g,
        (__attribute__((address_space(3))) void*)l, 16, 0, 0);
}

// ---------------- kernel 1: QKV projection (QBLK=32; vectorized x-stage) ----------------
#define K1_LDA 264  // 256 + 8 pad (shorts)

__global__ __launch_bounds__(256) void k_qkv(
    const float* __restrict__ x,
    const float* __restrict__ wq, const float* __restrict__ wk, const float* __restrict__ wv,
    const float* __restrict__ bq, const float* __restrict__ bk, const float* __restrict__ bv,
    unsigned short* __restrict__ Qb, unsigned short* __restrict__ Kb,
    unsigned short* __restrict__ Vt)
{
    __shared__ unsigned short lds[32 * K1_LDA];   // 16.9 KB
    const int b  = blockIdx.y;
    const int n0 = blockIdx.x * 32;
    const int t  = threadIdx.x;
    const int lane = t & 63, wv_ = t >> 6;
    const int g = lane >> 4, q16 = lane & 15;

    // stage x[b][c][n0+tok] -> lds[tok][c]; thread covers 4 consecutive tokens
    // x 8 channels via float4 loads (16B/lane, fully coalesced per 8-lane group).
    {
        int tk0 = (t & 7) * 4;                    // 4 consecutive tokens
        int cb  = (t >> 3) * 8;                   // 8 channels
        const float* xb = x + ((size_t)b * C_ * N_) + n0 + tk0;
        float4 col[8];
        #pragma unroll
        for (int e = 0; e < 8; ++e)
            col[e] = *(const float4*)&xb[(size_t)(cb + e) * N_];
        #pragma unroll
        for (int tk = 0; tk < 4; ++tk) {
            u16x8 v;
            #pragma unroll
            for (int e = 0; e < 8; ++e) {
                float f = (tk == 0) ? col[e].x : (tk == 1) ? col[e].y
                        : (tk == 2) ? col[e].z : col[e].w;
                v[e] = f2bf(f);
            }
            *(u16x8*)&lds[(tk0 + tk) * K1_LDA + cb] = v;
        }
    }
    __syncthreads();

    f32x4 acc[3][2][2];   // [tq][r2][nf]
    #pragma unroll
    for (int tq = 0; tq < 3; ++tq)
        #pragma unroll
        for (int r2 = 0; r2 < 2; ++r2)
            #pragma unroll
            for (int nf = 0; nf < 2; ++nf)
                acc[tq][r2][nf] = (f32x4){0.f, 0.f, 0.f, 0.f};

    const float* wsrc[3] = {wq, wk, wv};
    const int rbase = wv_ * 32;
    #pragma unroll
    for (int ks = 0; ks < 8; ++ks) {
        u16x8 a[2];
        #pragma unroll
        for (int nf = 0; nf < 2; ++nf)
            a[nf] = *(const u16x8*)&lds[(nf * 16 + q16) * K1_LDA + ks * 32 + g * 8];
        #pragma unroll
        for (int tq = 0; tq < 3; ++tq) {
            const float* w = wsrc[tq];
            #pragma unroll
            for (int r2 = 0; r2 < 2; ++r2) {
                u16x8 bf = ldw8(&w[(size_t)(rbase + r2 * 16 + q16) * 256 + ks * 32 + g * 8]);
                #pragma unroll
                for (int nf = 0; nf < 2; ++nf)
                    acc[tq][r2][nf] = mfma16(a[nf], bf, acc[tq][r2][nf]);
            }
        }
    }

    #pragma unroll
    for (int r2 = 0; r2 < 2; ++r2) {
        int r = rbase + r2 * 16 + q16;
        float biasq = bq[r], biask = bk[r];
        #pragma unroll
        for (int nf = 0; nf < 2; ++nf) {
            #pragma unroll
            for (int i = 0; i < 4; ++i) {
                int n = n0 + nf * 16 + g * 4 + i;
                size_t idx = ((size_t)b * N_ + n) * RC_ + r;
                Qb[idx] = f2bf((acc[0][r2][nf][i] + biasq) * SCALEL);
                Kb[idx] = f2bf(acc[1][r2][nf][i] + biask);
            }
        }
    }

    // V direct store in image layout (stride 36 shorts); this block = one key-tile.
    const size_t tile = (size_t)b * 128 + blockIdx.x;
    #pragma unroll
    for (int r2 = 0; r2 < 2; ++r2) {
        int r = rbase + r2 * 16 + q16;
        float biasv = bv[r];
        #pragma unroll
        for (int nf = 0; nf < 2; ++nf) {
            unsigned int w0 = (unsigned int)f2bf(acc[2][r2][nf][0] + biasv)
                            | ((unsigned int)f2bf(acc[2][r2][nf][1] + biasv) << 16);
            unsigned int w1 = (unsigned int)f2bf(acc[2][r2][nf][2] + biasv)
                            | ((unsigned int)f2bf(acc[2][r2][nf][3] + biasv) << 16);
            unsigned short* dst = Vt + (tile * 128 + r) * 36 + g * 8 + nf * 4;
            *(uint2*)dst = make_uint2(w0, w1);
        }
    }
}

// ---------------- kernel 2: flash attention (round-10 verified, frozen) ----------------
// 16 waves: qw = wv&1 (32 q-rows), grp = wv>>1 (512 keys, 16 tiles of 32).
// smem (shorts): Q [0,8192) 64x128 XOR-swz; K @8192+grp*4096: [32][128] XOR-swz (DMA);
//                V @40960+grp*4608: [128][36] image (linear DMA copy).
// merge overlay: l f32 @ [0,1024); U bf16 8x[64][132] @ [8192, 75776).
// Schedule per iter: QK | barrier A (drains V-DMA) | issue STAGEK(kt+1) |
//                    softmax | PV | barrier B (drains K-DMA) | issue STAGEV(kt+1)
__global__ __launch_bounds__(1024, 4) void k_attn(
    const unsigned short* __restrict__ Qb, const unsigned short* __restrict__ Kb,
    const unsigned short* __restrict__ Vt, unsigned short* __restrict__ Ob)
{
    __shared__ __align__(16) unsigned short smem[77824];   // 152 KiB
    const int b  = blockIdx.y;
    const int n0 = blockIdx.x * 64;
    const int t  = threadIdx.x;
    const int lane = t & 63, wv_ = t >> 6;        // 16 waves
    const int qw = wv_ & 1, grp = wv_ >> 1;       // 8 KV groups
    const int g = lane >> 4, q16 = lane & 15;

    unsigned short* Ql = smem;
    unsigned short* Kl = smem + 8192 + grp * 4096;
    unsigned short* Vl = smem + 40960 + grp * 4608;

    const unsigned short* Qg = Qb + ((size_t)b * N_ + n0) * RC_;
    const unsigned short* Kg = Kb + ((size_t)b * N_ + grp * 512) * RC_;
    const unsigned short* Vg = Vt + ((size_t)b * 128 + grp * 16) * 4608;

    // ---- Q stage: register path + XOR-swizzled ds_write ----
    {
        int sq = wv_ * 64 + lane;                 // 0..1023
        int row = sq >> 4, ch = sq & 15;
        uint4 v = *(const uint4*)&Qg[(size_t)row * RC_ + ch * 8];
        *(uint4*)&Ql[row * 128 + ((ch ^ (row & 7)) * 8)] = v;
    }

    // ---- DMA staging: wave-uniform LDS dest + per-lane (pre-swizzled) source ----
    #define STAGEK(kt_) do { int ktc = (kt_);                                    \
        _Pragma("unroll")                                                        \
        for (int r = 0; r < 4; ++r) {                                            \
            int m = qw * 4 + r;                                                  \
            int row = m * 4 + (lane >> 4);                                       \
            int ch = (lane & 15) ^ (row & 7);                                    \
            gl_lds16(Kg + (size_t)(ktc * 32 + row) * RC_ + ch * 8,               \
                     (char*)Kl + m * 1024);                                      \
        }                                                                        \
    } while (0)
    #define STAGEV(kt_) do { int ktc = (kt_);                                    \
        const char* vsrc = (const char*)(Vg + (size_t)ktc * 4608);               \
        char* vdst = (char*)Vl;                                                  \
        _Pragma("unroll")                                                        \
        for (int j = 0; j < 4; ++j) {                                            \
            int off = j * 2048 + qw * 1024;                                      \
            gl_lds16(vsrc + off + lane * 16, vdst + off);                        \
        }                                                                        \
        if (qw == 0)                                                             \
            gl_lds16(vsrc + 8192 + lane * 16, vdst + 8192);                      \
    } while (0)

    STAGEK(0);
    STAGEV(0);

    f32x4 acc_o[2][8];
    #pragma unroll
    for (int rf = 0; rf < 2; ++rf)
        #pragma unroll
        for (int df = 0; df < 8; ++df)
            acc_o[rf][df] = (f32x4){0.f, 0.f, 0.f, 0.f};
    float l_loc[2] = {0.f, 0.f};

    __syncthreads();   // Q ds_write + initial K/V DMA drained

    for (int kt = 0; kt < 16; ++kt) {
        // S^T = K Q^T (swapped): lane holds S[q = qblock + q16][k = kf*16 + g*4 + i]
        f32x4 s[2][2];
        #pragma unroll
        for (int rf = 0; rf < 2; ++rf)
            #pragma unroll
            for (int kf = 0; kf < 2; ++kf)
                s[rf][kf] = (f32x4){0.f, 0.f, 0.f, 0.f};
        __builtin_amdgcn_s_setprio(1);
        #pragma unroll
        for (int ks = 0; ks < 4; ++ks) {
            int sw = ((4 * ks + g) ^ (q16 & 7)) * 8;
            u16x8 qf0 = *(const u16x8*)&Ql[(qw * 32 + q16) * 128 + sw];
            u16x8 qf1 = *(const u16x8*)&Ql[(qw * 32 + 16 + q16) * 128 + sw];
            #pragma unroll
            for (int kf = 0; kf < 2; ++kf) {
                u16x8 kfr = *(const u16x8*)&Kl[(kf * 16 + q16) * 128 + sw];
                s[0][kf] = mfma16(kfr, qf0, s[0][kf]);
                s[1][kf] = mfma16(kfr, qf1, s[1][kf]);
            }
        }
        __builtin_amdgcn_s_setprio(0);

        __syncthreads();              // A: all QK reads of Kl done; V-DMA drained
        if (kt < 15) STAGEK(kt + 1);  // K-DMA flies under softmax + PV

        // no-max softmax: p = exp2(S') (log2e folded into Q); pack P via cvt_pk
        u16x8 pa[2];
        #pragma unroll
        for (int rf = 0; rf < 2; ++rf) {
            #pragma unroll
            for (int kf = 0; kf < 2; ++kf)
                #pragma unroll
                for (int i = 0; i < 4; ++i)
                    s[rf][kf][i] = exp2f(s[rf][kf][i]);
            l_loc[rf] += (s[rf][0][0] + s[rf][0][1]) + (s[rf][0][2] + s[rf][0][3])
                       + (s[rf][1][0] + s[rf][1][1]) + (s[rf][1][2] + s[rf][1][3]);
            int4 pk;
            pk.x = (int)cvtpk(s[rf][0][0], s[rf][0][1]);
            pk.y = (int)cvtpk(s[rf][0][2], s[rf][0][3]);
            pk.z = (int)cvtpk(s[rf][1][0], s[rf][1][1]);
            pk.w = (int)cvtpk(s[rf][1][2], s[rf][1][3]);
            pa[rf] = __builtin_bit_cast(u16x8, pk);
        }

        // O += P @ V.  V image row d: lane's 8 B-slots contiguous at short offset
        // g*8, read as two 8B chunks (stride 72B not 16B-aligned for odd d).
        __builtin_amdgcn_s_setprio(1);
        #pragma unroll
        for (int df = 0; df < 8; ++df) {
            int d = df * 16 + q16;
            const unsigned short* vrow = &Vl[d * 36 + g * 8];
            uint2 vlo = *(const uint2*)&vrow[0];
            uint2 vhi = *(const uint2*)&vrow[4];
            int4 vv = make_int4((int)vlo.x, (int)vlo.y, (int)vhi.x, (int)vhi.y);
            u16x8 vb = __builtin_bit_cast(u16x8, vv);
            acc_o[0][df] = mfma16(pa[0], vb, acc_o[0][df]);
            acc_o[1][df] = mfma16(pa[1], vb, acc_o[1][df]);
        }
        __builtin_amdgcn_s_setprio(0);

        __syncthreads();              // B: all PV reads of Vl done; K-DMA drained
        if (kt < 15) STAGEV(kt + 1);  // V-DMA flies under next iter's QK
    }

    // ---- merge across 8 KV groups ----
    float l0 = l_loc[0], l1 = l_loc[1];
    l0 += __shfl_xor(l0, 16); l0 += __shfl_xor(l0, 32);
    l1 += __shfl_xor(l1, 16); l1 += __shfl_xor(l1, 32);

    float* lf = (float*)smem;                       // [8 grp][64 rows]
    unsigned short* Ub = smem + 8192;               // [8 grp][64][132] bf16
    if (g == 0) {
        lf[grp * 64 + qw * 32 + q16]      = l0;
        lf[grp * 64 + qw * 32 + 16 + q16] = l1;
    }
    {
        unsigned short* Ug = Ub + grp * 8448;
        #pragma unroll
        for (int rf = 0; rf < 2; ++rf)
            #pragma unroll
            for (int df = 0; df < 8; ++df)
                #pragma unroll
                for (int i = 0; i < 4; ++i)
                    Ug[(qw * 32 + rf * 16 + g * 4 + i) * 132 + df * 16 + q16] =
                        f2bf(acc_o[rf][df][i]);
    }
    __syncthreads();

    // combine: wave wv_ handles q-rows [wv_*4, wv_*4+4), lane covers 2 d-cols
    #pragma unroll
    for (int r = 0; r < 4; ++r) {
        int row = wv_ * 4 + r;
        float lt = 0.f;
        #pragma unroll
        for (int gg = 0; gg < 8; ++gg) lt += lf[gg * 64 + row];
        float inv = 1.f / lt;
        float o0 = 0.f, o1 = 0.f;
        #pragma unroll
        for (int gg = 0; gg < 8; ++gg) {
            unsigned int u = *(const unsigned int*)&Ub[gg * 8448 + row * 132 + lane * 2];
            o0 += __builtin_bit_cast(float, u << 16);
            o1 += __builtin_bit_cast(float, u & 0xffff0000u);
        }
        unsigned int packed = ((unsigned int)f2bf(o1 * inv) << 16) | f2bf(o0 * inv);
        *(unsigned int*)&Ob[((size_t)b * N_ + n0 + row) * RC_ + lane * 2] = packed;
    }
    #undef STAGEK
    #undef STAGEV
}

// ---------------- kernel 3: output projection + residual (round-10 verified) ----------------
#define QS 136  // 128 + 8 pad (shorts)

__global__ __launch_bounds__(256) void k_out(
    const unsigned short* __restrict__ Ob, const float* __restrict__ wo,
    const float* __restrict__ bo, const float* __restrict__ x,
    const float* __restrict__ gamma, float* __restrict__ out)
{
    __shared__ unsigned short Ol[64 * QS];
    const int b  = blockIdx.z;
    const int c0 = blockIdx.y * 64;
    const int n0 = blockIdx.x * 64;
    const int t  = threadIdx.x;
    const int lane = t & 63, wv_ = t >> 6;
    const int g = lane >> 4, q16 = lane & 15;

    {
        const unsigned short* src = Ob + ((size_t)b * N_ + n0) * RC_;
        #pragma unroll
        for (int p = 0; p < 4; ++p) {
            int row = p * 16 + (t >> 4);
            int s = (t & 15) * 8;
            *(u16x8*)&Ol[row * QS + s] = *(const u16x8*)&src[row * RC_ + s];
        }
    }
    __syncthreads();

    f32x4 acc[4];
    #pragma unroll
    for (int nf = 0; nf < 4; ++nf)
        acc[nf] = (f32x4){0.f, 0.f, 0.f, 0.f};

    const int cw = c0 + wv_ * 16;
    #pragma unroll
    for (int ks = 0; ks < 4; ++ks) {
        u16x8 b8[4];
        #pragma unroll
        for (int nf = 0; nf < 4; ++nf)
            b8[nf] = *(const u16x8*)&Ol[(nf * 16 + q16) * QS + ks * 32 + g * 8];
        u16x8 a8 = ldw8(&wo[(size_t)(cw + q16) * 128 + ks * 32 + g * 8]);
        #pragma unroll
        for (int nf = 0; nf < 4; ++nf)
            acc[nf] = mfma16(a8, b8[nf], acc[nf]);
    }

    float gm = gamma[0];
    #pragma unroll
    for (int i = 0; i < 4; ++i) {
        int c = cw + g * 4 + i;
        float bias = bo[c];
        #pragma unroll
        for (int nf = 0; nf < 4; ++nf) {
            int n = n0 + nf * 16 + q16;
            size_t idx = ((size_t)b * C_ + c) * N_ + n;
            out[idx] = gm * (acc[nf][i] + bias) + x[idx];
        }
    }
}

extern "C" void kernel_launch(void* const* d_in, const int* in_sizes, int n_in,
                              void* d_out, int out_size, void* d_ws, size_t ws_size,
                              hipStream_t stream) {
    const float* x     = (const float*)d_in[0];
    const float* wq    = (const float*)d_in[1];
    const float* bq    = (const float*)d_in[2];
    const float* wk    = (const float*)d_in[3];
    const float* bk    = (const float*)d_in[4];
    const float* wv    = (const float*)d_in[5];
    const float* bv    = (const float*)d_in[6];
    const float* wo    = (const float*)d_in[7];
    const float* bo    = (const float*)d_in[8];
    const float* gamma = (const float*)d_in[9];
    float* out = (float*)d_out;

    unsigned short* ws = (unsigned short*)d_ws;
    unsigned short* Qb = ws;                   // [B][N][RC] bf16 (also reused as Ob)
    unsigned short* Kb = Qb + 2097152;         // [B][N][RC] bf16
    unsigned short* Vt = Kb + 2097152;         // [B*128 tiles][128][36] image
    unsigned short* Ob = Qb;                   // alias: k_attn reads Q only in prologue

    dim3 g1(128, 4);
    k_qkv<<<g1, 256, 0, stream>>>(x, wq, wk, wv, bq, bk, bv, Qb, Kb, Vt);
    dim3 g2(64, 4);
    k_attn<<<g2, 1024, 0, stream>>>(Qb, Kb, Vt, Ob);
    dim3 g3(64, 4, 4);
    k_out<<<g3, 256, 0, stream>>>(Ob, wo, bo, x, gamma, out);
}

// Round 14
// 88.805 us; speedup vs baseline: 1.1379x; 1.1120x over previous
//
#include <hip/hip_runtime.h>
#include <hip/hip_bf16.h>

// SelfAttentionBlock: B=4, C=256, RC=128, H=W=64 (N=4096)
// Round 14: fp8-e4m3 QK^T path. Q,K stored fp8 (raw values; SCALE*log2e moved
// into the exp2 argument); QK staging bytes and LDS fragment reads halve
// (ds_read_b64), QK mfma -> mfma_f32_16x16x32_fp8_fp8 (same rate as bf16).
// Softmax, P (bf16) and the V/PV path are unchanged from round 13 (verified).
// Ob gets its own workspace region (no longer aliasable with the 2MB Qf).

#define B_   4
#define C_   256
#define RC_  128
#define N_   4096
#define SCALEL 0.12750880597462906f                // (1/sqrt(128)) * log2(e)

typedef __bf16 bf16x8 __attribute__((ext_vector_type(8)));
typedef unsigned short u16x8 __attribute__((ext_vector_type(8)));
typedef float f32x4 __attribute__((ext_vector_type(4)));

static __device__ __forceinline__ unsigned short f2bf(float f) {
    unsigned int u = __builtin_bit_cast(unsigned int, f);
    u += 0x7fffu + ((u >> 16) & 1u);
    return (unsigned short)(u >> 16);
}

static __device__ __forceinline__ f32x4 mfma16(u16x8 a, u16x8 b, f32x4 c) {
    return __builtin_amdgcn_mfma_f32_16x16x32_bf16(
        __builtin_bit_cast(bf16x8, a), __builtin_bit_cast(bf16x8, b), c, 0, 0, 0);
}

static __device__ __forceinline__ unsigned int cvtpk(float lo, float hi) {
    unsigned int r;
    asm("v_cvt_pk_bf16_f32 %0, %1, %2" : "=v"(r) : "v"(lo), "v"(hi));
    return r;   // low 16 = bf16(lo), high 16 = bf16(hi), RNE
}

// load 8 consecutive f32 weights and pack to bf16x8 (same RNE as f2bf)
static __device__ __forceinline__ u16x8 ldw8(const float* p) {
    float4 f0 = *(const float4*)p;
    float4 f1 = *(const float4*)(p + 4);
    int4 pk;
    pk.x = (int)cvtpk(f0.x, f0.y);
    pk.y = (int)cvtpk(f0.z, f0.w);
    pk.z = (int)cvtpk(f1.x, f1.y);
    pk.w = (int)cvtpk(f1.z, f1.w);
    return __builtin_bit_cast(u16x8, pk);
}

static __device__ __forceinline__ void gl_lds16(const void* g, void* l) {
    __builtin_amdgcn_global_load_lds(
        (const __attribute__((address_space(1))) void*)g,
        (__attribute__((address_space(3))) void*)l, 16, 0, 0);
}

// ---------------- kernel 1: QKV projection (QBLK=32; fp8 Q/K out) ----------------
#define K1_LDA 264  // 256 + 8 pad (shorts)

__global__ __launch_bounds__(256) void k_qkv(
    const float* __restrict__ x,
    const float* __restrict__ wq, const float* __restrict__ wk, const float* __restrict__ wv,
    const float* __restrict__ bq, const float* __restrict__ bk, const float* __restrict__ bv,
    unsigned char* __restrict__ Qf, unsigned char* __restrict__ Kf,
    unsigned short* __restrict__ Vt)
{
    __shared__ unsigned short lds[32 * K1_LDA];   // 16.9 KB
    const int b  = blockIdx.y;
    const int n0 = blockIdx.x * 32;
    const int t  = threadIdx.x;
    const int lane = t & 63, wv_ = t >> 6;
    const int g = lane >> 4, q16 = lane & 15;

    // stage x[b][c][n0+tok] -> lds[tok][c]; float4 over 4 consecutive tokens
    {
        int tk0 = (t & 7) * 4;
        int cb  = (t >> 3) * 8;
        const float* xb = x + ((size_t)b * C_ * N_) + n0 + tk0;
        float4 col[8];
        #pragma unroll
        for (int e = 0; e < 8; ++e)
            col[e] = *(const float4*)&xb[(size_t)(cb + e) * N_];
        #pragma unroll
        for (int tk = 0; tk < 4; ++tk) {
            u16x8 v;
            #pragma unroll
            for (int e = 0; e < 8; ++e) {
                float f = (tk == 0) ? col[e].x : (tk == 1) ? col[e].y
                        : (tk == 2) ? col[e].z : col[e].w;
                v[e] = f2bf(f);
            }
            *(u16x8*)&lds[(tk0 + tk) * K1_LDA + cb] = v;
        }
    }
    __syncthreads();

    f32x4 acc[3][2][2];   // [tq][r2][nf]
    #pragma unroll
    for (int tq = 0; tq < 3; ++tq)
        #pragma unroll
        for (int r2 = 0; r2 < 2; ++r2)
            #pragma unroll
            for (int nf = 0; nf < 2; ++nf)
                acc[tq][r2][nf] = (f32x4){0.f, 0.f, 0.f, 0.f};

    const float* wsrc[3] = {wq, wk, wv};
    const int rbase = wv_ * 32;
    #pragma unroll
    for (int ks = 0; ks < 8; ++ks) {
        u16x8 a[2];
        #pragma unroll
        for (int nf = 0; nf < 2; ++nf)
            a[nf] = *(const u16x8*)&lds[(nf * 16 + q16) * K1_LDA + ks * 32 + g * 8];
        #pragma unroll
        for (int tq = 0; tq < 3; ++tq) {
            const float* w = wsrc[tq];
            #pragma unroll
            for (int r2 = 0; r2 < 2; ++r2) {
                u16x8 bf = ldw8(&w[(size_t)(rbase + r2 * 16 + q16) * 256 + ks * 32 + g * 8]);
                #pragma unroll
                for (int nf = 0; nf < 2; ++nf)
                    acc[tq][r2][nf] = mfma16(a[nf], bf, acc[tq][r2][nf]);
            }
        }
    }

    // Q, K: fp8 e4m3 stores (raw values; softmax applies SCALEL later)
    #pragma unroll
    for (int r2 = 0; r2 < 2; ++r2) {
        int r = rbase + r2 * 16 + q16;
        float biasq = bq[r], biask = bk[r];
        #pragma unroll
        for (int nf = 0; nf < 2; ++nf) {
            int nb = n0 + nf * 16 + g * 4;
            int pq0 = __builtin_amdgcn_cvt_pk_fp8_f32(acc[0][r2][nf][0] + biasq,
                                                      acc[0][r2][nf][1] + biasq, 0, false);
            int pq1 = __builtin_amdgcn_cvt_pk_fp8_f32(acc[0][r2][nf][2] + biasq,
                                                      acc[0][r2][nf][3] + biasq, 0, false);
            int pk0 = __builtin_amdgcn_cvt_pk_fp8_f32(acc[1][r2][nf][0] + biask,
                                                      acc[1][r2][nf][1] + biask, 0, false);
            int pk1 = __builtin_amdgcn_cvt_pk_fp8_f32(acc[1][r2][nf][2] + biask,
                                                      acc[1][r2][nf][3] + biask, 0, false);
            unsigned char qv[4] = {(unsigned char)(pq0 & 255), (unsigned char)((pq0 >> 8) & 255),
                                   (unsigned char)(pq1 & 255), (unsigned char)((pq1 >> 8) & 255)};
            unsigned char kv[4] = {(unsigned char)(pk0 & 255), (unsigned char)((pk0 >> 8) & 255),
                                   (unsigned char)(pk1 & 255), (unsigned char)((pk1 >> 8) & 255)};
            #pragma unroll
            for (int i = 0; i < 4; ++i) {
                size_t idx = ((size_t)b * N_ + nb + i) * RC_ + r;
                Qf[idx] = qv[i];
                Kf[idx] = kv[i];
            }
        }
    }

    // V direct store in image layout (stride 36 shorts); this block = one key-tile.
    const size_t tile = (size_t)b * 128 + blockIdx.x;
    #pragma unroll
    for (int r2 = 0; r2 < 2; ++r2) {
        int r = rbase + r2 * 16 + q16;
        float biasv = bv[r];
        #pragma unroll
        for (int nf = 0; nf < 2; ++nf) {
            unsigned int w0 = (unsigned int)f2bf(acc[2][r2][nf][0] + biasv)
                            | ((unsigned int)f2bf(acc[2][r2][nf][1] + biasv) << 16);
            unsigned int w1 = (unsigned int)f2bf(acc[2][r2][nf][2] + biasv)
                            | ((unsigned int)f2bf(acc[2][r2][nf][3] + biasv) << 16);
            unsigned short* dst = Vt + (tile * 128 + r) * 36 + g * 8 + nf * 4;
            *(uint2*)dst = make_uint2(w0, w1);
        }
    }
}

// ---------------- kernel 2: flash attention (fp8 QK^T, bf16 PV) ----------------
// 16 waves: qw = wv&1 (32 q-rows), grp = wv>>1 (512 keys, 16 tiles of 32).
// smem bytes: Q fp8 [0,8192) 64x128B XOR-swz(16B chunks);
//             K fp8 @16384+grp*8192 (4KB used): [32][128B] XOR-swz (DMA);
//             V bf16 @81920+grp*9216: [128][36] image (linear DMA copy).
// merge overlay: l f32 @ byte 0; U bf16 8x[64][132] @ byte 16384 (unchanged).
__global__ __launch_bounds__(1024, 4) void k_attn(
    const unsigned char* __restrict__ Qf, const unsigned char* __restrict__ Kf,
    const unsigned short* __restrict__ Vt, unsigned short* __restrict__ Ob)
{
    __shared__ __align__(16) unsigned short smem[77824];   // 152 KiB
    const int b  = blockIdx.y;
    const int n0 = blockIdx.x * 64;
    const int t  = threadIdx.x;
    const int lane = t & 63, wv_ = t >> 6;        // 16 waves
    const int qw = wv_ & 1, grp = wv_ >> 1;       // 8 KV groups
    const int g = lane >> 4, q16 = lane & 15;

    unsigned char* Ql8 = (unsigned char*)smem;                       // 8KB
    unsigned char* Klb = (unsigned char*)smem + 16384 + grp * 8192;  // 4KB used
    unsigned short* Vl = smem + 40960 + grp * 4608;                  // byte 81920+

    const unsigned char* Qg = Qf + ((size_t)b * N_ + n0) * RC_;
    const unsigned char* Kg = Kf + ((size_t)b * N_ + grp * 512) * RC_;
    const unsigned short* Vg = Vt + ((size_t)b * 128 + grp * 16) * 4608;

    // ---- Q stage: 512 threads, 16B chunks, XOR-swizzled ds_write ----
    if (t < 512) {
        int row = t >> 3, ch = t & 7;
        uint4 v = *(const uint4*)&Qg[row * 128 + ch * 16];
        *(uint4*)&Ql8[row * 128 + ((ch ^ (row & 7)) * 16)] = v;
    }

    // ---- DMA staging ----
    #define STAGEK(kt_) do { int ktc = (kt_);                                    \
        _Pragma("unroll")                                                        \
        for (int r = 0; r < 2; ++r) {                                            \
            int id = (qw * 2 + r) * 64 + lane;   /* 0..255 chunks of 16B */      \
            int row = id >> 3, ch = id & 7;                                      \
            gl_lds16(Kg + (size_t)(ktc * 32 + row) * RC_ + ((ch ^ (row & 7)) * 16), \
                     Klb + (qw * 2 + r) * 1024);                                 \
        }                                                                        \
    } while (0)
    #define STAGEV(kt_) do { int ktc = (kt_);                                    \
        const char* vsrc = (const char*)(Vg + (size_t)ktc * 4608);               \
        char* vdst = (char*)Vl;                                                  \
        _Pragma("unroll")                                                        \
        for (int j = 0; j < 4; ++j) {                                            \
            int off = j * 2048 + qw * 1024;                                      \
            gl_lds16(vsrc + off + lane * 16, vdst + off);                        \
        }                                                                        \
        if (qw == 0)                                                             \
            gl_lds16(vsrc + 8192 + lane * 16, vdst + 8192);                      \
    } while (0)

    STAGEK(0);
    STAGEV(0);

    f32x4 acc_o[2][8];
    #pragma unroll
    for (int rf = 0; rf < 2; ++rf)
        #pragma unroll
        for (int df = 0; df < 8; ++df)
            acc_o[rf][df] = (f32x4){0.f, 0.f, 0.f, 0.f};
    float l_loc[2] = {0.f, 0.f};

    __syncthreads();   // Q ds_write + initial K/V DMA drained

    for (int kt = 0; kt < 16; ++kt) {
        // S^T = K Q^T (swapped, fp8): lane holds S[q=qblock+q16][k=kf*16+g*4+i].
        // 8B k-slot o = 4ks+g; addr = row*128 + ((o>>1)^(q16&7))*16 + (o&1)*8.
        f32x4 s[2][2];
        #pragma unroll
        for (int rf = 0; rf < 2; ++rf)
            #pragma unroll
            for (int kf = 0; kf < 2; ++kf)
                s[rf][kf] = (f32x4){0.f, 0.f, 0.f, 0.f};
        __builtin_amdgcn_s_setprio(1);
        #pragma unroll
        for (int ks = 0; ks < 4; ++ks) {
            int sw = (((2 * ks + (g >> 1)) ^ (q16 & 7)) * 16) + ((g & 1) * 8);
            long qv0 = *(const long*)&Ql8[(qw * 32 + q16) * 128 + sw];
            long qv1 = *(const long*)&Ql8[(qw * 32 + 16 + q16) * 128 + sw];
            #pragma unroll
            for (int kf = 0; kf < 2; ++kf) {
                long kv = *(const long*)&Klb[(kf * 16 + q16) * 128 + sw];
                s[0][kf] = __builtin_amdgcn_mfma_f32_16x16x32_fp8_fp8(kv, qv0, s[0][kf], 0, 0, 0);
                s[1][kf] = __builtin_amdgcn_mfma_f32_16x16x32_fp8_fp8(kv, qv1, s[1][kf], 0, 0, 0);
            }
        }
        __builtin_amdgcn_s_setprio(0);

        __syncthreads();              // A: all QK reads of Klb done; V-DMA drained
        if (kt < 15) STAGEK(kt + 1);  // K-DMA flies under softmax + PV

        // no-max softmax: p = exp2(S * SCALEL); pack P via cvt_pk
        u16x8 pa[2];
        #pragma unroll
        for (int rf = 0; rf < 2; ++rf) {
            #pragma unroll
            for (int kf = 0; kf < 2; ++kf)
                #pragma unroll
                for (int i = 0; i < 4; ++i)
                    s[rf][kf][i] = exp2f(s[rf][kf][i] * SCALEL);
            l_loc[rf] += (s[rf][0][0] + s[rf][0][1]) + (s[rf][0][2] + s[rf][0][3])
                       + (s[rf][1][0] + s[rf][1][1]) + (s[rf][1][2] + s[rf][1][3]);
            int4 pk;
            pk.x = (int)cvtpk(s[rf][0][0], s[rf][0][1]);
            pk.y = (int)cvtpk(s[rf][0][2], s[rf][0][3]);
            pk.z = (int)cvtpk(s[rf][1][0], s[rf][1][1]);
            pk.w = (int)cvtpk(s[rf][1][2], s[rf][1][3]);
            pa[rf] = __builtin_bit_cast(u16x8, pk);
        }

        // O += P @ V (bf16, unchanged). V image row d: 8 B-slots at short g*8.
        __builtin_amdgcn_s_setprio(1);
        #pragma unroll
        for (int df = 0; df < 8; ++df) {
            int d = df * 16 + q16;
            const unsigned short* vrow = &Vl[d * 36 + g * 8];
            uint2 vlo = *(const uint2*)&vrow[0];
            uint2 vhi = *(const uint2*)&vrow[4];
            int4 vv = make_int4((int)vlo.x, (int)vlo.y, (int)vhi.x, (int)vhi.y);
            u16x8 vb = __builtin_bit_cast(u16x8, vv);
            acc_o[0][df] = mfma16(pa[0], vb, acc_o[0][df]);
            acc_o[1][df] = mfma16(pa[1], vb, acc_o[1][df]);
        }
        __builtin_amdgcn_s_setprio(0);

        __syncthreads();              // B: all PV reads of Vl done; K-DMA drained
        if (kt < 15) STAGEV(kt + 1);  // V-DMA flies under next iter's QK
    }

    // ---- merge across 8 KV groups (unchanged layout) ----
    float l0 = l_loc[0], l1 = l_loc[1];
    l0 += __shfl_xor(l0, 16); l0 += __shfl_xor(l0, 32);
    l1 += __shfl_xor(l1, 16); l1 += __shfl_xor(l1, 32);

    float* lf = (float*)smem;                       // [8 grp][64 rows]
    unsigned short* Ub = smem + 8192;               // [8 grp][64][132] bf16 @byte 16384
    if (g == 0) {
        lf[grp * 64 + qw * 32 + q16]      = l0;
        lf[grp * 64 + qw * 32 + 16 + q16] = l1;
    }
    {
        unsigned short* Ug = Ub + grp * 8448;
        #pragma unroll
        for (int rf = 0; rf < 2; ++rf)
            #pragma unroll
            for (int df = 0; df < 8; ++df)
                #pragma unroll
                for (int i = 0; i < 4; ++i)
                    Ug[(qw * 32 + rf * 16 + g * 4 + i) * 132 + df * 16 + q16] =
                        f2bf(acc_o[rf][df][i]);
    }
    __syncthreads();

    // combine: wave wv_ handles q-rows [wv_*4, wv_*4+4), lane covers 2 d-cols
    #pragma unroll
    for (int r = 0; r < 4; ++r) {
        int row = wv_ * 4 + r;
        float lt = 0.f;
        #pragma unroll
        for (int gg = 0; gg < 8; ++gg) lt += lf[gg * 64 + row];
        float inv = 1.f / lt;
        float o0 = 0.f, o1 = 0.f;
        #pragma unroll
        for (int gg = 0; gg < 8; ++gg) {
            unsigned int u = *(const unsigned int*)&Ub[gg * 8448 + row * 132 + lane * 2];
            o0 += __builtin_bit_cast(float, u << 16);
            o1 += __builtin_bit_cast(float, u & 0xffff0000u);
        }
        unsigned int packed = ((unsigned int)f2bf(o1 * inv) << 16) | f2bf(o0 * inv);
        *(unsigned int*)&Ob[((size_t)b * N_ + n0 + row) * RC_ + lane * 2] = packed;
    }
    #undef STAGEK
    #undef STAGEV
}

// ---------------- kernel 3: output projection + residual (round-10 verified) ----------------
#define QS 136  // 128 + 8 pad (shorts)

__global__ __launch_bounds__(256) void k_out(
    const unsigned short* __restrict__ Ob, const float* __restrict__ wo,
    const float* __restrict__ bo, const float* __restrict__ x,
    const float* __restrict__ gamma, float* __restrict__ out)
{
    __shared__ unsigned short Ol[64 * QS];
    const int b  = blockIdx.z;
    const int c0 = blockIdx.y * 64;
    const int n0 = blockIdx.x * 64;
    const int t  = threadIdx.x;
    const int lane = t & 63, wv_ = t >> 6;
    const int g = lane >> 4, q16 = lane & 15;

    {
        const unsigned short* src = Ob + ((size_t)b * N_ + n0) * RC_;
        #pragma unroll
        for (int p = 0; p < 4; ++p) {
            int row = p * 16 + (t >> 4);
            int s = (t & 15) * 8;
            *(u16x8*)&Ol[row * QS + s] = *(const u16x8*)&src[row * RC_ + s];
        }
    }
    __syncthreads();

    f32x4 acc[4];
    #pragma unroll
    for (int nf = 0; nf < 4; ++nf)
        acc[nf] = (f32x4){0.f, 0.f, 0.f, 0.f};

    const int cw = c0 + wv_ * 16;
    #pragma unroll
    for (int ks = 0; ks < 4; ++ks) {
        u16x8 b8[4];
        #pragma unroll
        for (int nf = 0; nf < 4; ++nf)
            b8[nf] = *(const u16x8*)&Ol[(nf * 16 + q16) * QS + ks * 32 + g * 8];
        u16x8 a8 = ldw8(&wo[(size_t)(cw + q16) * 128 + ks * 32 + g * 8]);
        #pragma unroll
        for (int nf = 0; nf < 4; ++nf)
            acc[nf] = mfma16(a8, b8[nf], acc[nf]);
    }

    float gm = gamma[0];
    #pragma unroll
    for (int i = 0; i < 4; ++i) {
        int c = cw + g * 4 + i;
        float bias = bo[c];
        #pragma unroll
        for (int nf = 0; nf < 4; ++nf) {
            int n = n0 + nf * 16 + q16;
            size_t idx = ((size_t)b * C_ + c) * N_ + n;
            out[idx] = gm * (acc[nf][i] + bias) + x[idx];
        }
    }
}

extern "C" void kernel_launch(void* const* d_in, const int* in_sizes, int n_in,
                              void* d_out, int out_size, void* d_ws, size_t ws_size,
                              hipStream_t stream) {
    const float* x     = (const float*)d_in[0];
    const float* wq    = (const float*)d_in[1];
    const float* bq    = (const float*)d_in[2];
    const float* wk    = (const float*)d_in[3];
    const float* bk    = (const float*)d_in[4];
    const float* wv    = (const float*)d_in[5];
    const float* bv    = (const float*)d_in[6];
    const float* wo    = (const float*)d_in[7];
    const float* bo    = (const float*)d_in[8];
    const float* gamma = (const float*)d_in[9];
    float* out = (float*)d_out;

    unsigned char* wsb = (unsigned char*)d_ws;
    unsigned char* Qf  = wsb;                               // [B][N][RC] fp8, 2MB
    unsigned char* Kf  = wsb + 2097152;                     // [B][N][RC] fp8, 2MB
    unsigned short* Vt = (unsigned short*)(wsb + 4194304);  // [B*128][128][36] bf16, 4.72MB
    unsigned short* Ob = (unsigned short*)(wsb + 8912896);  // [B][N][RC] bf16, 4MB

    dim3 g1(128, 4);
    k_qkv<<<g1, 256, 0, stream>>>(x, wq, wk, wv, bq, bk, bv, Qf, Kf, Vt);
    dim3 g2(64, 4);
    k_attn<<<g2, 1024, 0, stream>>>(Qf, Kf, Vt, Ob);
    dim3 g3(64, 4, 4);
    k_out<<<g3, 256, 0, stream>>>(Ob, wo, bo, x, gamma, out);
}

// Round 15
// 85.464 us; speedup vs baseline: 1.1824x; 1.0391x over previous
//
#include <hip/hip_runtime.h>
#include <hip/hip_bf16.h>

// SelfAttentionBlock: B=4, C=256, RC=128, H=W=64 (N=4096)
// Round 15: fp8 extended to the P·V path. V stored fp8-e4m3 in a [128][40]B
// per-tile image; P packed fp8 via cvt_pk_fp8_f32; PV = mfma fp8_fp8.
// PV fragment reads halve (8x ds_read_b64), V staging bytes -30%.
// QK fp8 path, softmax, merge, k_out unchanged from round 14 (verified).

#define B_   4
#define C_   256
#define RC_  128
#define N_   4096
#define SCALEL 0.12750880597462906f                // (1/sqrt(128)) * log2(e)

typedef __bf16 bf16x8 __attribute__((ext_vector_type(8)));
typedef unsigned short u16x8 __attribute__((ext_vector_type(8)));
typedef float f32x4 __attribute__((ext_vector_type(4)));

static __device__ __forceinline__ unsigned short f2bf(float f) {
    unsigned int u = __builtin_bit_cast(unsigned int, f);
    u += 0x7fffu + ((u >> 16) & 1u);
    return (unsigned short)(u >> 16);
}

static __device__ __forceinline__ f32x4 mfma16(u16x8 a, u16x8 b, f32x4 c) {
    return __builtin_amdgcn_mfma_f32_16x16x32_bf16(
        __builtin_bit_cast(bf16x8, a), __builtin_bit_cast(bf16x8, b), c, 0, 0, 0);
}

static __device__ __forceinline__ unsigned int cvtpk(float lo, float hi) {
    unsigned int r;
    asm("v_cvt_pk_bf16_f32 %0, %1, %2" : "=v"(r) : "v"(lo), "v"(hi));
    return r;   // low 16 = bf16(lo), high 16 = bf16(hi), RNE
}

// load 8 consecutive f32 weights and pack to bf16x8 (same RNE as f2bf)
static __device__ __forceinline__ u16x8 ldw8(const float* p) {
    float4 f0 = *(const float4*)p;
    float4 f1 = *(const float4*)(p + 4);
    int4 pk;
    pk.x = (int)cvtpk(f0.x, f0.y);
    pk.y = (int)cvtpk(f0.z, f0.w);
    pk.z = (int)cvtpk(f1.x, f1.y);
    pk.w = (int)cvtpk(f1.z, f1.w);
    return __builtin_bit_cast(u16x8, pk);
}

// pack 4 f32 -> 4 fp8 e4m3 bytes
static __device__ __forceinline__ int pk4fp8(float a, float b, float c, float d) {
    int w = __builtin_amdgcn_cvt_pk_fp8_f32(a, b, 0, false);
    w = __builtin_amdgcn_cvt_pk_fp8_f32(c, d, w, true);
    return w;
}

static __device__ __forceinline__ void gl_lds16(const void* g, void* l) {
    __builtin_amdgcn_global_load_lds(
        (const __attribute__((address_space(1))) void*)g,
        (__attribute__((address_space(3))) void*)l, 16, 0, 0);
}

// ---------------- kernel 1: QKV projection (QBLK=32; fp8 Q/K/V out) ----------------
#define K1_LDA 264  // 256 + 8 pad (shorts)

__global__ __launch_bounds__(256) void k_qkv(
    const float* __restrict__ x,
    const float* __restrict__ wq, const float* __restrict__ wk, const float* __restrict__ wv,
    const float* __restrict__ bq, const float* __restrict__ bk, const float* __restrict__ bv,
    unsigned char* __restrict__ Qf, unsigned char* __restrict__ Kf,
    unsigned char* __restrict__ Vt8)
{
    __shared__ unsigned short lds[32 * K1_LDA];   // 16.9 KB
    const int b  = blockIdx.y;
    const int n0 = blockIdx.x * 32;
    const int t  = threadIdx.x;
    const int lane = t & 63, wv_ = t >> 6;
    const int g = lane >> 4, q16 = lane & 15;

    // stage x[b][c][n0+tok] -> lds[tok][c]; float4 over 4 consecutive tokens
    {
        int tk0 = (t & 7) * 4;
        int cb  = (t >> 3) * 8;
        const float* xb = x + ((size_t)b * C_ * N_) + n0 + tk0;
        float4 col[8];
        #pragma unroll
        for (int e = 0; e < 8; ++e)
            col[e] = *(const float4*)&xb[(size_t)(cb + e) * N_];
        #pragma unroll
        for (int tk = 0; tk < 4; ++tk) {
            u16x8 v;
            #pragma unroll
            for (int e = 0; e < 8; ++e) {
                float f = (tk == 0) ? col[e].x : (tk == 1) ? col[e].y
                        : (tk == 2) ? col[e].z : col[e].w;
                v[e] = f2bf(f);
            }
            *(u16x8*)&lds[(tk0 + tk) * K1_LDA + cb] = v;
        }
    }
    __syncthreads();

    f32x4 acc[3][2][2];   // [tq][r2][nf]
    #pragma unroll
    for (int tq = 0; tq < 3; ++tq)
        #pragma unroll
        for (int r2 = 0; r2 < 2; ++r2)
            #pragma unroll
            for (int nf = 0; nf < 2; ++nf)
                acc[tq][r2][nf] = (f32x4){0.f, 0.f, 0.f, 0.f};

    const float* wsrc[3] = {wq, wk, wv};
    const int rbase = wv_ * 32;
    #pragma unroll
    for (int ks = 0; ks < 8; ++ks) {
        u16x8 a[2];
        #pragma unroll
        for (int nf = 0; nf < 2; ++nf)
            a[nf] = *(const u16x8*)&lds[(nf * 16 + q16) * K1_LDA + ks * 32 + g * 8];
        #pragma unroll
        for (int tq = 0; tq < 3; ++tq) {
            const float* w = wsrc[tq];
            #pragma unroll
            for (int r2 = 0; r2 < 2; ++r2) {
                u16x8 bf = ldw8(&w[(size_t)(rbase + r2 * 16 + q16) * 256 + ks * 32 + g * 8]);
                #pragma unroll
                for (int nf = 0; nf < 2; ++nf)
                    acc[tq][r2][nf] = mfma16(a[nf], bf, acc[tq][r2][nf]);
            }
        }
    }

    // Q, K: fp8 e4m3 stores (raw values; softmax applies SCALEL later)
    #pragma unroll
    for (int r2 = 0; r2 < 2; ++r2) {
        int r = rbase + r2 * 16 + q16;
        float biasq = bq[r], biask = bk[r];
        #pragma unroll
        for (int nf = 0; nf < 2; ++nf) {
            int nb = n0 + nf * 16 + g * 4;
            int pq0 = __builtin_amdgcn_cvt_pk_fp8_f32(acc[0][r2][nf][0] + biasq,
                                                      acc[0][r2][nf][1] + biasq, 0, false);
            int pq1 = __builtin_amdgcn_cvt_pk_fp8_f32(acc[0][r2][nf][2] + biasq,
                                                      acc[0][r2][nf][3] + biasq, 0, false);
            int pk0 = __builtin_amdgcn_cvt_pk_fp8_f32(acc[1][r2][nf][0] + biask,
                                                      acc[1][r2][nf][1] + biask, 0, false);
            int pk1 = __builtin_amdgcn_cvt_pk_fp8_f32(acc[1][r2][nf][2] + biask,
                                                      acc[1][r2][nf][3] + biask, 0, false);
            unsigned char qv[4] = {(unsigned char)(pq0 & 255), (unsigned char)((pq0 >> 8) & 255),
                                   (unsigned char)(pq1 & 255), (unsigned char)((pq1 >> 8) & 255)};
            unsigned char kv[4] = {(unsigned char)(pk0 & 255), (unsigned char)((pk0 >> 8) & 255),
                                   (unsigned char)(pk1 & 255), (unsigned char)((pk1 >> 8) & 255)};
            #pragma unroll
            for (int i = 0; i < 4; ++i) {
                size_t idx = ((size_t)b * N_ + nb + i) * RC_ + r;
                Qf[idx] = qv[i];
                Kf[idx] = kv[i];
            }
        }
    }

    // V: fp8 e4m3 image, stride 40 B per channel row; this block = one key-tile.
    // Value for key k = nf*16 + g*4 + i at channel r -> byte position g*8 + nf*4 + i.
    const size_t tile = (size_t)b * 128 + blockIdx.x;
    #pragma unroll
    for (int r2 = 0; r2 < 2; ++r2) {
        int r = rbase + r2 * 16 + q16;
        float biasv = bv[r];
        #pragma unroll
        for (int nf = 0; nf < 2; ++nf) {
            int w = pk4fp8(acc[2][r2][nf][0] + biasv, acc[2][r2][nf][1] + biasv,
                           acc[2][r2][nf][2] + biasv, acc[2][r2][nf][3] + biasv);
            *(unsigned int*)(Vt8 + (tile * 128 + r) * 40 + g * 8 + nf * 4) = (unsigned int)w;
        }
    }
}

// ---------------- kernel 2: flash attention (fp8 QK^T and PV) ----------------
// 16 waves: qw = wv&1 (32 q-rows), grp = wv>>1 (512 keys, 16 tiles of 32).
// smem bytes: Q fp8 [0,8192) 64x128B XOR-swz(16B chunks);
//             K fp8 @16384+grp*8192 (4KB used): [32][128B] XOR-swz (DMA);
//             V fp8 @81920+grp*5120: [128][40]B image (linear DMA copy).
// merge overlay: l f32 @ byte 0; U bf16 8x[64][132] @ byte 16384 (unchanged).
__global__ __launch_bounds__(1024, 4) void k_attn(
    const unsigned char* __restrict__ Qf, const unsigned char* __restrict__ Kf,
    const unsigned char* __restrict__ Vt8, unsigned short* __restrict__ Ob)
{
    __shared__ __align__(16) unsigned short smem[77824];   // 152 KiB
    const int b  = blockIdx.y;
    const int n0 = blockIdx.x * 64;
    const int t  = threadIdx.x;
    const int lane = t & 63, wv_ = t >> 6;        // 16 waves
    const int qw = wv_ & 1, grp = wv_ >> 1;       // 8 KV groups
    const int g = lane >> 4, q16 = lane & 15;

    unsigned char* Ql8 = (unsigned char*)smem;                       // 8KB
    unsigned char* Klb = (unsigned char*)smem + 16384 + grp * 8192;  // 4KB used
    unsigned char* Vl8 = (unsigned char*)smem + 81920 + grp * 5120;  // 5KB

    const unsigned char* Qg = Qf + ((size_t)b * N_ + n0) * RC_;
    const unsigned char* Kg = Kf + ((size_t)b * N_ + grp * 512) * RC_;
    const unsigned char* Vg = Vt8 + ((size_t)b * 128 + grp * 16) * 5120;

    // ---- Q stage: 512 threads, 16B chunks, XOR-swizzled ds_write ----
    if (t < 512) {
        int row = t >> 3, ch = t & 7;
        uint4 v = *(const uint4*)&Qg[row * 128 + ch * 16];
        *(uint4*)&Ql8[row * 128 + ((ch ^ (row & 7)) * 16)] = v;
    }

    // ---- DMA staging ----
    #define STAGEK(kt_) do { int ktc = (kt_);                                    \
        _Pragma("unroll")                                                        \
        for (int r = 0; r < 2; ++r) {                                            \
            int id = (qw * 2 + r) * 64 + lane;   /* 0..255 chunks of 16B */      \
            int row = id >> 3, ch = id & 7;                                      \
            gl_lds16(Kg + (size_t)(ktc * 32 + row) * RC_ + ((ch ^ (row & 7)) * 16), \
                     Klb + (qw * 2 + r) * 1024);                                 \
        }                                                                        \
    } while (0)
    #define STAGEV(kt_) do { int ktc = (kt_);                                    \
        const char* vsrc = (const char*)(Vg + (size_t)ktc * 5120);               \
        char* vdst = (char*)Vl8;                                                 \
        _Pragma("unroll")                                                        \
        for (int j = 0; j < 2; ++j) {                                            \
            int off = j * 2048 + qw * 1024;                                      \
            gl_lds16(vsrc + off + lane * 16, vdst + off);                        \
        }                                                                        \
        if (qw == 0)                                                             \
            gl_lds16(vsrc + 4096 + lane * 16, vdst + 4096);                      \
    } while (0)

    STAGEK(0);
    STAGEV(0);

    f32x4 acc_o[2][8];
    #pragma unroll
    for (int rf = 0; rf < 2; ++rf)
        #pragma unroll
        for (int df = 0; df < 8; ++df)
            acc_o[rf][df] = (f32x4){0.f, 0.f, 0.f, 0.f};
    float l_loc[2] = {0.f, 0.f};

    __syncthreads();   // Q ds_write + initial K/V DMA drained

    for (int kt = 0; kt < 16; ++kt) {
        // S^T = K Q^T (swapped, fp8): lane holds S[q=qblock+q16][k=kf*16+g*4+i].
        f32x4 s[2][2];
        #pragma unroll
        for (int rf = 0; rf < 2; ++rf)
            #pragma unroll
            for (int kf = 0; kf < 2; ++kf)
                s[rf][kf] = (f32x4){0.f, 0.f, 0.f, 0.f};
        __builtin_amdgcn_s_setprio(1);
        #pragma unroll
        for (int ks = 0; ks < 4; ++ks) {
            int sw = (((2 * ks + (g >> 1)) ^ (q16 & 7)) * 16) + ((g & 1) * 8);
            long qv0 = *(const long*)&Ql8[(qw * 32 + q16) * 128 + sw];
            long qv1 = *(const long*)&Ql8[(qw * 32 + 16 + q16) * 128 + sw];
            #pragma unroll
            for (int kf = 0; kf < 2; ++kf) {
                long kv = *(const long*)&Klb[(kf * 16 + q16) * 128 + sw];
                s[0][kf] = __builtin_amdgcn_mfma_f32_16x16x32_fp8_fp8(kv, qv0, s[0][kf], 0, 0, 0);
                s[1][kf] = __builtin_amdgcn_mfma_f32_16x16x32_fp8_fp8(kv, qv1, s[1][kf], 0, 0, 0);
            }
        }
        __builtin_amdgcn_s_setprio(0);

        __syncthreads();              // A: all QK reads of Klb done; V-DMA drained
        if (kt < 15) STAGEK(kt + 1);  // K-DMA flies under softmax + PV

        // no-max softmax: p = exp2(S * SCALEL); pack P to fp8 (max p ~ 2^6 << 448)
        long pa8[2];
        #pragma unroll
        for (int rf = 0; rf < 2; ++rf) {
            #pragma unroll
            for (int kf = 0; kf < 2; ++kf)
                #pragma unroll
                for (int i = 0; i < 4; ++i)
                    s[rf][kf][i] = exp2f(s[rf][kf][i] * SCALEL);
            l_loc[rf] += (s[rf][0][0] + s[rf][0][1]) + (s[rf][0][2] + s[rf][0][3])
                       + (s[rf][1][0] + s[rf][1][1]) + (s[rf][1][2] + s[rf][1][3]);
            int2 pk2;
            pk2.x = pk4fp8(s[rf][0][0], s[rf][0][1], s[rf][0][2], s[rf][0][3]);
            pk2.y = pk4fp8(s[rf][1][0], s[rf][1][1], s[rf][1][2], s[rf][1][3]);
            pa8[rf] = __builtin_bit_cast(long, pk2);
        }

        // O += P @ V (fp8). V image row d: lane's 8 byte-slots at g*8 (one b64).
        __builtin_amdgcn_s_setprio(1);
        #pragma unroll
        for (int df = 0; df < 8; ++df) {
            int d = df * 16 + q16;
            long vv = *(const long*)&Vl8[d * 40 + g * 8];
            acc_o[0][df] = __builtin_amdgcn_mfma_f32_16x16x32_fp8_fp8(pa8[0], vv, acc_o[0][df], 0, 0, 0);
            acc_o[1][df] = __builtin_amdgcn_mfma_f32_16x16x32_fp8_fp8(pa8[1], vv, acc_o[1][df], 0, 0, 0);
        }
        __builtin_amdgcn_s_setprio(0);

        __syncthreads();              // B: all PV reads of Vl8 done; K-DMA drained
        if (kt < 15) STAGEV(kt + 1);  // V-DMA flies under next iter's QK
    }

    // ---- merge across 8 KV groups (unchanged layout) ----
    float l0 = l_loc[0], l1 = l_loc[1];
    l0 += __shfl_xor(l0, 16); l0 += __shfl_xor(l0, 32);
    l1 += __shfl_xor(l1, 16); l1 += __shfl_xor(l1, 32);

    float* lf = (float*)smem;                       // [8 grp][64 rows]
    unsigned short* Ub = smem + 8192;               // [8 grp][64][132] bf16 @byte 16384
    if (g == 0) {
        lf[grp * 64 + qw * 32 + q16]      = l0;
        lf[grp * 64 + qw * 32 + 16 + q16] = l1;
    }
    {
        unsigned short* Ug = Ub + grp * 8448;
        #pragma unroll
        for (int rf = 0; rf < 2; ++rf)
            #pragma unroll
            for (int df = 0; df < 8; ++df)
                #pragma unroll
                for (int i = 0; i < 4; ++i)
                    Ug[(qw * 32 + rf * 16 + g * 4 + i) * 132 + df * 16 + q16] =
                        f2bf(acc_o[rf][df][i]);
    }
    __syncthreads();

    // combine: wave wv_ handles q-rows [wv_*4, wv_*4+4), lane covers 2 d-cols
    #pragma unroll
    for (int r = 0; r < 4; ++r) {
        int row = wv_ * 4 + r;
        float lt = 0.f;
        #pragma unroll
        for (int gg = 0; gg < 8; ++gg) lt += lf[gg * 64 + row];
        float inv = 1.f / lt;
        float o0 = 0.f, o1 = 0.f;
        #pragma unroll
        for (int gg = 0; gg < 8; ++gg) {
            unsigned int u = *(const unsigned int*)&Ub[gg * 8448 + row * 132 + lane * 2];
            o0 += __builtin_bit_cast(float, u << 16);
            o1 += __builtin_bit_cast(float, u & 0xffff0000u);
        }
        unsigned int packed = ((unsigned int)f2bf(o1 * inv) << 16) | f2bf(o0 * inv);
        *(unsigned int*)&Ob[((size_t)b * N_ + n0 + row) * RC_ + lane * 2] = packed;
    }
    #undef STAGEK
    #undef STAGEV
}

// ---------------- kernel 3: output projection + residual (round-10 verified) ----------------
#define QS 136  // 128 + 8 pad (shorts)

__global__ __launch_bounds__(256) void k_out(
    const unsigned short* __restrict__ Ob, const float* __restrict__ wo,
    const float* __restrict__ bo, const float* __restrict__ x,
    const float* __restrict__ gamma, float* __restrict__ out)
{
    __shared__ unsigned short Ol[64 * QS];
    const int b  = blockIdx.z;
    const int c0 = blockIdx.y * 64;
    const int n0 = blockIdx.x * 64;
    const int t  = threadIdx.x;
    const int lane = t & 63, wv_ = t >> 6;
    const int g = lane >> 4, q16 = lane & 15;

    {
        const unsigned short* src = Ob + ((size_t)b * N_ + n0) * RC_;
        #pragma unroll
        for (int p = 0; p < 4; ++p) {
            int row = p * 16 + (t >> 4);
            int s = (t & 15) * 8;
            *(u16x8*)&Ol[row * QS + s] = *(const u16x8*)&src[row * RC_ + s];
        }
    }
    __syncthreads();

    f32x4 acc[4];
    #pragma unroll
    for (int nf = 0; nf < 4; ++nf)
        acc[nf] = (f32x4){0.f, 0.f, 0.f, 0.f};

    const int cw = c0 + wv_ * 16;
    #pragma unroll
    for (int ks = 0; ks < 4; ++ks) {
        u16x8 b8[4];
        #pragma unroll
        for (int nf = 0; nf < 4; ++nf)
            b8[nf] = *(const u16x8*)&Ol[(nf * 16 + q16) * QS + ks * 32 + g * 8];
        u16x8 a8 = ldw8(&wo[(size_t)(cw + q16) * 128 + ks * 32 + g * 8]);
        #pragma unroll
        for (int nf = 0; nf < 4; ++nf)
            acc[nf] = mfma16(a8, b8[nf], acc[nf]);
    }

    float gm = gamma[0];
    #pragma unroll
    for (int i = 0; i < 4; ++i) {
        int c = cw + g * 4 + i;
        float bias = bo[c];
        #pragma unroll
        for (int nf = 0; nf < 4; ++nf) {
            int n = n0 + nf * 16 + q16;
            size_t idx = ((size_t)b * C_ + c) * N_ + n;
            out[idx] = gm * (acc[nf][i] + bias) + x[idx];
        }
    }
}

extern "C" void kernel_launch(void* const* d_in, const int* in_sizes, int n_in,
                              void* d_out, int out_size, void* d_ws, size_t ws_size,
                              hipStream_t stream) {
    const float* x     = (const float*)d_in[0];
    const float* wq    = (const float*)d_in[1];
    const float* bq    = (const float*)d_in[2];
    const float* wk    = (const float*)d_in[3];
    const float* bk    = (const float*)d_in[4];
    const float* wv    = (const float*)d_in[5];
    const float* bv    = (const float*)d_in[6];
    const float* wo    = (const float*)d_in[7];
    const float* bo    = (const float*)d_in[8];
    const float* gamma = (const float*)d_in[9];
    float* out = (float*)d_out;

    unsigned char* wsb = (unsigned char*)d_ws;
    unsigned char* Qf  = wsb;                               // [B][N][RC] fp8, 2MB
    unsigned char* Kf  = wsb + 2097152;                     // [B][N][RC] fp8, 2MB
    unsigned char* Vt8 = wsb + 4194304;                     // [B*128][128][40]B fp8 image, 2.62MB
    unsigned short* Ob = (unsigned short*)(wsb + 6815744);  // [B][N][RC] bf16, 4MB

    dim3 g1(128, 4);
    k_qkv<<<g1, 256, 0, stream>>>(x, wq, wk, wv, bq, bk, bv, Qf, Kf, Vt8);
    dim3 g2(64, 4);
    k_attn<<<g2, 1024, 0, stream>>>(Qf, Kf, Vt8, Ob);
    dim3 g3(64, 4, 4);
    k_out<<<g3, 256, 0, stream>>>(Ob, wo, bo, x, gamma, out);
}

// Round 16
// 84.183 us; speedup vs baseline: 1.2004x; 1.0152x over previous
//
#include <hip/hip_runtime.h>
#include <hip/hip_bf16.h>

// SelfAttentionBlock: B=4, C=256, RC=128, H=W=64 (N=4096)
// Round 16 (on round-15 verified base, 85.5us):
//  (1) k_qkv: Q/K computed with swapped-operand MFMA (A=w, B=x) so each thread
//      holds 4 consecutive r per token -> Q/K stores become 8 dword stores
//      (was 32 byte-stores). Fragment loads unchanged; V path unchanged.
//  (2) SCALE*log2e folded into Q's fp8 quantization; k_attn softmax is a bare
//      exp2 (16 fewer VALU muls/wave-iter).

#define B_   4
#define C_   256
#define RC_  128
#define N_   4096
#define SCALEL 0.12750880597462906f                // (1/sqrt(128)) * log2(e)

typedef __bf16 bf16x8 __attribute__((ext_vector_type(8)));
typedef unsigned short u16x8 __attribute__((ext_vector_type(8)));
typedef float f32x4 __attribute__((ext_vector_type(4)));

static __device__ __forceinline__ unsigned short f2bf(float f) {
    unsigned int u = __builtin_bit_cast(unsigned int, f);
    u += 0x7fffu + ((u >> 16) & 1u);
    return (unsigned short)(u >> 16);
}

static __device__ __forceinline__ f32x4 mfma16(u16x8 a, u16x8 b, f32x4 c) {
    return __builtin_amdgcn_mfma_f32_16x16x32_bf16(
        __builtin_bit_cast(bf16x8, a), __builtin_bit_cast(bf16x8, b), c, 0, 0, 0);
}

static __device__ __forceinline__ unsigned int cvtpk(float lo, float hi) {
    unsigned int r;
    asm("v_cvt_pk_bf16_f32 %0, %1, %2" : "=v"(r) : "v"(lo), "v"(hi));
    return r;   // low 16 = bf16(lo), high 16 = bf16(hi), RNE
}

// load 8 consecutive f32 weights and pack to bf16x8 (same RNE as f2bf)
static __device__ __forceinline__ u16x8 ldw8(const float* p) {
    float4 f0 = *(const float4*)p;
    float4 f1 = *(const float4*)(p + 4);
    int4 pk;
    pk.x = (int)cvtpk(f0.x, f0.y);
    pk.y = (int)cvtpk(f0.z, f0.w);
    pk.z = (int)cvtpk(f1.x, f1.y);
    pk.w = (int)cvtpk(f1.z, f1.w);
    return __builtin_bit_cast(u16x8, pk);
}

// pack 4 f32 -> 4 fp8 e4m3 bytes
static __device__ __forceinline__ int pk4fp8(float a, float b, float c, float d) {
    int w = __builtin_amdgcn_cvt_pk_fp8_f32(a, b, 0, false);
    w = __builtin_amdgcn_cvt_pk_fp8_f32(c, d, w, true);
    return w;
}

static __device__ __forceinline__ void gl_lds16(const void* g, void* l) {
    __builtin_amdgcn_global_load_lds(
        (const __attribute__((address_space(1))) void*)g,
        (__attribute__((address_space(3))) void*)l, 16, 0, 0);
}

// ---------------- kernel 1: QKV projection (QBLK=32; fp8 Q/K/V out) ----------------
#define K1_LDA 264  // 256 + 8 pad (shorts)

__global__ __launch_bounds__(256) void k_qkv(
    const float* __restrict__ x,
    const float* __restrict__ wq, const float* __restrict__ wk, const float* __restrict__ wv,
    const float* __restrict__ bq, const float* __restrict__ bk, const float* __restrict__ bv,
    unsigned char* __restrict__ Qf, unsigned char* __restrict__ Kf,
    unsigned char* __restrict__ Vt8)
{
    __shared__ unsigned short lds[32 * K1_LDA];   // 16.9 KB
    const int b  = blockIdx.y;
    const int n0 = blockIdx.x * 32;
    const int t  = threadIdx.x;
    const int lane = t & 63, wv_ = t >> 6;
    const int g = lane >> 4, q16 = lane & 15;

    // stage x[b][c][n0+tok] -> lds[tok][c]; float4 over 4 consecutive tokens
    {
        int tk0 = (t & 7) * 4;
        int cb  = (t >> 3) * 8;
        const float* xb = x + ((size_t)b * C_ * N_) + n0 + tk0;
        float4 col[8];
        #pragma unroll
        for (int e = 0; e < 8; ++e)
            col[e] = *(const float4*)&xb[(size_t)(cb + e) * N_];
        #pragma unroll
        for (int tk = 0; tk < 4; ++tk) {
            u16x8 v;
            #pragma unroll
            for (int e = 0; e < 8; ++e) {
                float f = (tk == 0) ? col[e].x : (tk == 1) ? col[e].y
                        : (tk == 2) ? col[e].z : col[e].w;
                v[e] = f2bf(f);
            }
            *(u16x8*)&lds[(tk0 + tk) * K1_LDA + cb] = v;
        }
    }
    __syncthreads();

    // acc[0]=Q, acc[1]=K (swapped operands: thread holds r = rbase+r2*16+g*4+i,
    //                     n = n0+nf*16+q16)
    // acc[2]=V (original order: thread holds r = rbase+r2*16+q16,
    //                     n = n0+nf*16+g*4+i)
    f32x4 acc[3][2][2];   // [tq][r2][nf]
    #pragma unroll
    for (int tq = 0; tq < 3; ++tq)
        #pragma unroll
        for (int r2 = 0; r2 < 2; ++r2)
            #pragma unroll
            for (int nf = 0; nf < 2; ++nf)
                acc[tq][r2][nf] = (f32x4){0.f, 0.f, 0.f, 0.f};

    const float* wsrc[3] = {wq, wk, wv};
    const int rbase = wv_ * 32;
    #pragma unroll
    for (int ks = 0; ks < 8; ++ks) {
        u16x8 a[2];
        #pragma unroll
        for (int nf = 0; nf < 2; ++nf)
            a[nf] = *(const u16x8*)&lds[(nf * 16 + q16) * K1_LDA + ks * 32 + g * 8];
        #pragma unroll
        for (int tq = 0; tq < 3; ++tq) {
            const float* w = wsrc[tq];
            #pragma unroll
            for (int r2 = 0; r2 < 2; ++r2) {
                u16x8 bf = ldw8(&w[(size_t)(rbase + r2 * 16 + q16) * 256 + ks * 32 + g * 8]);
                #pragma unroll
                for (int nf = 0; nf < 2; ++nf) {
                    if (tq < 2)
                        acc[tq][r2][nf] = mfma16(bf, a[nf], acc[tq][r2][nf]);  // swapped
                    else
                        acc[tq][r2][nf] = mfma16(a[nf], bf, acc[tq][r2][nf]);
                }
            }
        }
    }

    // Q (pre-scaled by SCALEL), K: fp8 e4m3 dword stores (4 consecutive r/thread)
    #pragma unroll
    for (int r2 = 0; r2 < 2; ++r2) {
        int rb = rbase + r2 * 16 + g * 4;
        float4 bq4 = *(const float4*)&bq[rb];
        float4 bk4 = *(const float4*)&bk[rb];
        #pragma unroll
        for (int nf = 0; nf < 2; ++nf) {
            int n = n0 + nf * 16 + q16;
            int qw32 = pk4fp8((acc[0][r2][nf][0] + bq4.x) * SCALEL,
                              (acc[0][r2][nf][1] + bq4.y) * SCALEL,
                              (acc[0][r2][nf][2] + bq4.z) * SCALEL,
                              (acc[0][r2][nf][3] + bq4.w) * SCALEL);
            int kw32 = pk4fp8(acc[1][r2][nf][0] + bk4.x, acc[1][r2][nf][1] + bk4.y,
                              acc[1][r2][nf][2] + bk4.z, acc[1][r2][nf][3] + bk4.w);
            size_t base = ((size_t)b * N_ + n) * RC_ + rb;
            *(unsigned int*)(Qf + base) = (unsigned int)qw32;
            *(unsigned int*)(Kf + base) = (unsigned int)kw32;
        }
    }

    // V: fp8 e4m3 image, stride 40 B per channel row; this block = one key-tile.
    // Value for key k = nf*16 + g*4 + i at channel r -> byte position g*8 + nf*4 + i.
    const size_t tile = (size_t)b * 128 + blockIdx.x;
    #pragma unroll
    for (int r2 = 0; r2 < 2; ++r2) {
        int r = rbase + r2 * 16 + q16;
        float biasv = bv[r];
        #pragma unroll
        for (int nf = 0; nf < 2; ++nf) {
            int w = pk4fp8(acc[2][r2][nf][0] + biasv, acc[2][r2][nf][1] + biasv,
                           acc[2][r2][nf][2] + biasv, acc[2][r2][nf][3] + biasv);
            *(unsigned int*)(Vt8 + (tile * 128 + r) * 40 + g * 8 + nf * 4) = (unsigned int)w;
        }
    }
}

// ---------------- kernel 2: flash attention (fp8 QK^T and PV) ----------------
// 16 waves: qw = wv&1 (32 q-rows), grp = wv>>1 (512 keys, 16 tiles of 32).
// smem bytes: Q fp8 [0,8192) 64x128B XOR-swz(16B chunks);
//             K fp8 @16384+grp*8192 (4KB used): [32][128B] XOR-swz (DMA);
//             V fp8 @81920+grp*5120: [128][40]B image (linear DMA copy).
// merge overlay: l f32 @ byte 0; U bf16 8x[64][132] @ byte 16384 (unchanged).
__global__ __launch_bounds__(1024, 4) void k_attn(
    const unsigned char* __restrict__ Qf, const unsigned char* __restrict__ Kf,
    const unsigned char* __restrict__ Vt8, unsigned short* __restrict__ Ob)
{
    __shared__ __align__(16) unsigned short smem[77824];   // 152 KiB
    const int b  = blockIdx.y;
    const int n0 = blockIdx.x * 64;
    const int t  = threadIdx.x;
    const int lane = t & 63, wv_ = t >> 6;        // 16 waves
    const int qw = wv_ & 1, grp = wv_ >> 1;       // 8 KV groups
    const int g = lane >> 4, q16 = lane & 15;

    unsigned char* Ql8 = (unsigned char*)smem;                       // 8KB
    unsigned char* Klb = (unsigned char*)smem + 16384 + grp * 8192;  // 4KB used
    unsigned char* Vl8 = (unsigned char*)smem + 81920 + grp * 5120;  // 5KB

    const unsigned char* Qg = Qf + ((size_t)b * N_ + n0) * RC_;
    const unsigned char* Kg = Kf + ((size_t)b * N_ + grp * 512) * RC_;
    const unsigned char* Vg = Vt8 + ((size_t)b * 128 + grp * 16) * 5120;

    // ---- Q stage: 512 threads, 16B chunks, XOR-swizzled ds_write ----
    if (t < 512) {
        int row = t >> 3, ch = t & 7;
        uint4 v = *(const uint4*)&Qg[row * 128 + ch * 16];
        *(uint4*)&Ql8[row * 128 + ((ch ^ (row & 7)) * 16)] = v;
    }

    // ---- DMA staging ----
    #define STAGEK(kt_) do { int ktc = (kt_);                                    \
        _Pragma("unroll")                                                        \
        for (int r = 0; r < 2; ++r) {                                            \
            int id = (qw * 2 + r) * 64 + lane;   /* 0..255 chunks of 16B */      \
            int row = id >> 3, ch = id & 7;                                      \
            gl_lds16(Kg + (size_t)(ktc * 32 + row) * RC_ + ((ch ^ (row & 7)) * 16), \
                     Klb + (qw * 2 + r) * 1024);                                 \
        }                                                                        \
    } while (0)
    #define STAGEV(kt_) do { int ktc = (kt_);                                    \
        const char* vsrc = (const char*)(Vg + (size_t)ktc * 5120);               \
        char* vdst = (char*)Vl8;                                                 \
        _Pragma("unroll")                                                        \
        for (int j = 0; j < 2; ++j) {                                            \
            int off = j * 2048 + qw * 1024;                                      \
            gl_lds16(vsrc + off + lane * 16, vdst + off);                        \
        }                                                                        \
        if (qw == 0)                                                             \
            gl_lds16(vsrc + 4096 + lane * 16, vdst + 4096);                      \
    } while (0)

    STAGEK(0);
    STAGEV(0);

    f32x4 acc_o[2][8];
    #pragma unroll
    for (int rf = 0; rf < 2; ++rf)
        #pragma unroll
        for (int df = 0; df < 8; ++df)
            acc_o[rf][df] = (f32x4){0.f, 0.f, 0.f, 0.f};
    float l_loc[2] = {0.f, 0.f};

    __syncthreads();   // Q ds_write + initial K/V DMA drained

    for (int kt = 0; kt < 16; ++kt) {
        // S^T = K Q^T (swapped, fp8): lane holds S[q=qblock+q16][k=kf*16+g*4+i].
        f32x4 s[2][2];
        #pragma unroll
        for (int rf = 0; rf < 2; ++rf)
            #pragma unroll
            for (int kf = 0; kf < 2; ++kf)
                s[rf][kf] = (f32x4){0.f, 0.f, 0.f, 0.f};
        __builtin_amdgcn_s_setprio(1);
        #pragma unroll
        for (int ks = 0; ks < 4; ++ks) {
            int sw = (((2 * ks + (g >> 1)) ^ (q16 & 7)) * 16) + ((g & 1) * 8);
            long qv0 = *(const long*)&Ql8[(qw * 32 + q16) * 128 + sw];
            long qv1 = *(const long*)&Ql8[(qw * 32 + 16 + q16) * 128 + sw];
            #pragma unroll
            for (int kf = 0; kf < 2; ++kf) {
                long kv = *(const long*)&Klb[(kf * 16 + q16) * 128 + sw];
                s[0][kf] = __builtin_amdgcn_mfma_f32_16x16x32_fp8_fp8(kv, qv0, s[0][kf], 0, 0, 0);
                s[1][kf] = __builtin_amdgcn_mfma_f32_16x16x32_fp8_fp8(kv, qv1, s[1][kf], 0, 0, 0);
            }
        }
        __builtin_amdgcn_s_setprio(0);

        __syncthreads();              // A: all QK reads of Klb done; V-DMA drained
        if (kt < 15) STAGEK(kt + 1);  // K-DMA flies under softmax + PV

        // no-max softmax: p = exp2(S) (SCALEL pre-folded into Q); pack P to fp8
        long pa8[2];
        #pragma unroll
        for (int rf = 0; rf < 2; ++rf) {
            #pragma unroll
            for (int kf = 0; kf < 2; ++kf)
                #pragma unroll
                for (int i = 0; i < 4; ++i)
                    s[rf][kf][i] = exp2f(s[rf][kf][i]);
            l_loc[rf] += (s[rf][0][0] + s[rf][0][1]) + (s[rf][0][2] + s[rf][0][3])
                       + (s[rf][1][0] + s[rf][1][1]) + (s[rf][1][2] + s[rf][1][3]);
            int2 pk2;
            pk2.x = pk4fp8(s[rf][0][0], s[rf][0][1], s[rf][0][2], s[rf][0][3]);
            pk2.y = pk4fp8(s[rf][1][0], s[rf][1][1], s[rf][1][2], s[rf][1][3]);
            pa8[rf] = __builtin_bit_cast(long, pk2);
        }

        // O += P @ V (fp8). V image row d: lane's 8 byte-slots at g*8 (one b64).
        __builtin_amdgcn_s_setprio(1);
        #pragma unroll
        for (int df = 0; df < 8; ++df) {
            int d = df * 16 + q16;
            long vv = *(const long*)&Vl8[d * 40 + g * 8];
            acc_o[0][df] = __builtin_amdgcn_mfma_f32_16x16x32_fp8_fp8(pa8[0], vv, acc_o[0][df], 0, 0, 0);
            acc_o[1][df] = __builtin_amdgcn_mfma_f32_16x16x32_fp8_fp8(pa8[1], vv, acc_o[1][df], 0, 0, 0);
        }
        __builtin_amdgcn_s_setprio(0);

        __syncthreads();              // B: all PV reads of Vl8 done; K-DMA drained
        if (kt < 15) STAGEV(kt + 1);  // V-DMA flies under next iter's QK
    }

    // ---- merge across 8 KV groups (unchanged layout) ----
    float l0 = l_loc[0], l1 = l_loc[1];
    l0 += __shfl_xor(l0, 16); l0 += __shfl_xor(l0, 32);
    l1 += __shfl_xor(l1, 16); l1 += __shfl_xor(l1, 32);

    float* lf = (float*)smem;                       // [8 grp][64 rows]
    unsigned short* Ub = smem + 8192;               // [8 grp][64][132] bf16 @byte 16384
    if (g == 0) {
        lf[grp * 64 + qw * 32 + q16]      = l0;
        lf[grp * 64 + qw * 32 + 16 + q16] = l1;
    }
    {
        unsigned short* Ug = Ub + grp * 8448;
        #pragma unroll
        for (int rf = 0; rf < 2; ++rf)
            #pragma unroll
            for (int df = 0; df < 8; ++df)
                #pragma unroll
                for (int i = 0; i < 4; ++i)
                    Ug[(qw * 32 + rf * 16 + g * 4 + i) * 132 + df * 16 + q16] =
                        f2bf(acc_o[rf][df][i]);
    }
    __syncthreads();

    // combine: wave wv_ handles q-rows [wv_*4, wv_*4+4), lane covers 2 d-cols
    #pragma unroll
    for (int r = 0; r < 4; ++r) {
        int row = wv_ * 4 + r;
        float lt = 0.f;
        #pragma unroll
        for (int gg = 0; gg < 8; ++gg) lt += lf[gg * 64 + row];
        float inv = 1.f / lt;
        float o0 = 0.f, o1 = 0.f;
        #pragma unroll
        for (int gg = 0; gg < 8; ++gg) {
            unsigned int u = *(const unsigned int*)&Ub[gg * 8448 + row * 132 + lane * 2];
            o0 += __builtin_bit_cast(float, u << 16);
            o1 += __builtin_bit_cast(float, u & 0xffff0000u);
        }
        unsigned int packed = ((unsigned int)f2bf(o1 * inv) << 16) | f2bf(o0 * inv);
        *(unsigned int*)&Ob[((size_t)b * N_ + n0 + row) * RC_ + lane * 2] = packed;
    }
    #undef STAGEK
    #undef STAGEV
}

// ---------------- kernel 3: output projection + residual (round-10 verified) ----------------
#define QS 136  // 128 + 8 pad (shorts)

__global__ __launch_bounds__(256) void k_out(
    const unsigned short* __restrict__ Ob, const float* __restrict__ wo,
    const float* __restrict__ bo, const float* __restrict__ x,
    const float* __restrict__ gamma, float* __restrict__ out)
{
    __shared__ unsigned short Ol[64 * QS];
    const int b  = blockIdx.z;
    const int c0 = blockIdx.y * 64;
    const int n0 = blockIdx.x * 64;
    const int t  = threadIdx.x;
    const int lane = t & 63, wv_ = t >> 6;
    const int g = lane >> 4, q16 = lane & 15;

    {
        const unsigned short* src = Ob + ((size_t)b * N_ + n0) * RC_;
        #pragma unroll
        for (int p = 0; p < 4; ++p) {
            int row = p * 16 + (t >> 4);
            int s = (t & 15) * 8;
            *(u16x8*)&Ol[row * QS + s] = *(const u16x8*)&src[row * RC_ + s];
        }
    }
    __syncthreads();

    f32x4 acc[4];
    #pragma unroll
    for (int nf = 0; nf < 4; ++nf)
        acc[nf] = (f32x4){0.f, 0.f, 0.f, 0.f};

    const int cw = c0 + wv_ * 16;
    #pragma unroll
    for (int ks = 0; ks < 4; ++ks) {
        u16x8 b8[4];
        #pragma unroll
        for (int nf = 0; nf < 4; ++nf)
            b8[nf] = *(const u16x8*)&Ol[(nf * 16 + q16) * QS + ks * 32 + g * 8];
        u16x8 a8 = ldw8(&wo[(size_t)(cw + q16) * 128 + ks * 32 + g * 8]);
        #pragma unroll
        for (int nf = 0; nf < 4; ++nf)
            acc[nf] = mfma16(a8, b8[nf], acc[nf]);
    }

    float gm = gamma[0];
    #pragma unroll
    for (int i = 0; i < 4; ++i) {
        int c = cw + g * 4 + i;
        float bias = bo[c];
        #pragma unroll
        for (int nf = 0; nf < 4; ++nf) {
            int n = n0 + nf * 16 + q16;
            size_t idx = ((size_t)b * C_ + c) * N_ + n;
            out[idx] = gm * (acc[nf][i] + bias) + x[idx];
        }
    }
}

extern "C" void kernel_launch(void* const* d_in, const int* in_sizes, int n_in,
                              void* d_out, int out_size, void* d_ws, size_t ws_size,
                              hipStream_t stream) {
    const float* x     = (const float*)d_in[0];
    const float* wq    = (const float*)d_in[1];
    const float* bq    = (const float*)d_in[2];
    const float* wk    = (const float*)d_in[3];
    const float* bk    = (const float*)d_in[4];
    const float* wv    = (const float*)d_in[5];
    const float* bv    = (const float*)d_in[6];
    const float* wo    = (const float*)d_in[7];
    const float* bo    = (const float*)d_in[8];
    const float* gamma = (const float*)d_in[9];
    float* out = (float*)d_out;

    unsigned char* wsb = (unsigned char*)d_ws;
    unsigned char* Qf  = wsb;                               // [B][N][RC] fp8, 2MB
    unsigned char* Kf  = wsb + 2097152;                     // [B][N][RC] fp8, 2MB
    unsigned char* Vt8 = wsb + 4194304;                     // [B*128][128][40]B fp8 image, 2.62MB
    unsigned short* Ob = (unsigned short*)(wsb + 6815744);  // [B][N][RC] bf16, 4MB

    dim3 g1(128, 4);
    k_qkv<<<g1, 256, 0, stream>>>(x, wq, wk, wv, bq, bk, bv, Qf, Kf, Vt8);
    dim3 g2(64, 4);
    k_attn<<<g2, 1024, 0, stream>>>(Qf, Kf, Vt8, Ob);
    dim3 g3(64, 4, 4);
    k_out<<<g3, 256, 0, stream>>>(Ob, wo, bo, x, gamma, out);
}

// Round 17
// 81.431 us; speedup vs baseline: 1.2410x; 1.0338x over previous
//
#include <hip/hip_runtime.h>
#include <hip/hip_bf16.h>

// SelfAttentionBlock: B=4, C=256, RC=128, H=W=64 (N=4096)
// Round 17: k_attn K/V double-buffered -> ONE barrier per iteration (2-phase
// T3 recipe). DMA for tile kt+1 issues at loop top into buf[p^1] and has the
// whole iteration to fly; single end-of-iter barrier drains it and fences
// buffer reuse. LDS: Q 8KB + K 2x4KB/grp + V 2x5KB/grp = 155648 B (unchanged
// total). k_qkv / k_out identical to round 16 (verified, 84.2us).

#define B_   4
#define C_   256
#define RC_  128
#define N_   4096
#define SCALEL 0.12750880597462906f                // (1/sqrt(128)) * log2(e)

typedef __bf16 bf16x8 __attribute__((ext_vector_type(8)));
typedef unsigned short u16x8 __attribute__((ext_vector_type(8)));
typedef float f32x4 __attribute__((ext_vector_type(4)));

static __device__ __forceinline__ unsigned short f2bf(float f) {
    unsigned int u = __builtin_bit_cast(unsigned int, f);
    u += 0x7fffu + ((u >> 16) & 1u);
    return (unsigned short)(u >> 16);
}

static __device__ __forceinline__ f32x4 mfma16(u16x8 a, u16x8 b, f32x4 c) {
    return __builtin_amdgcn_mfma_f32_16x16x32_bf16(
        __builtin_bit_cast(bf16x8, a), __builtin_bit_cast(bf16x8, b), c, 0, 0, 0);
}

static __device__ __forceinline__ unsigned int cvtpk(float lo, float hi) {
    unsigned int r;
    asm("v_cvt_pk_bf16_f32 %0, %1, %2" : "=v"(r) : "v"(lo), "v"(hi));
    return r;   // low 16 = bf16(lo), high 16 = bf16(hi), RNE
}

// load 8 consecutive f32 weights and pack to bf16x8 (same RNE as f2bf)
static __device__ __forceinline__ u16x8 ldw8(const float* p) {
    float4 f0 = *(const float4*)p;
    float4 f1 = *(const float4*)(p + 4);
    int4 pk;
    pk.x = (int)cvtpk(f0.x, f0.y);
    pk.y = (int)cvtpk(f0.z, f0.w);
    pk.z = (int)cvtpk(f1.x, f1.y);
    pk.w = (int)cvtpk(f1.z, f1.w);
    return __builtin_bit_cast(u16x8, pk);
}

// pack 4 f32 -> 4 fp8 e4m3 bytes
static __device__ __forceinline__ int pk4fp8(float a, float b, float c, float d) {
    int w = __builtin_amdgcn_cvt_pk_fp8_f32(a, b, 0, false);
    w = __builtin_amdgcn_cvt_pk_fp8_f32(c, d, w, true);
    return w;
}

static __device__ __forceinline__ void gl_lds16(const void* g, void* l) {
    __builtin_amdgcn_global_load_lds(
        (const __attribute__((address_space(1))) void*)g,
        (__attribute__((address_space(3))) void*)l, 16, 0, 0);
}

// ---------------- kernel 1: QKV projection (round-16 verified) ----------------
#define K1_LDA 264  // 256 + 8 pad (shorts)

__global__ __launch_bounds__(256) void k_qkv(
    const float* __restrict__ x,
    const float* __restrict__ wq, const float* __restrict__ wk, const float* __restrict__ wv,
    const float* __restrict__ bq, const float* __restrict__ bk, const float* __restrict__ bv,
    unsigned char* __restrict__ Qf, unsigned char* __restrict__ Kf,
    unsigned char* __restrict__ Vt8)
{
    __shared__ unsigned short lds[32 * K1_LDA];   // 16.9 KB
    const int b  = blockIdx.y;
    const int n0 = blockIdx.x * 32;
    const int t  = threadIdx.x;
    const int lane = t & 63, wv_ = t >> 6;
    const int g = lane >> 4, q16 = lane & 15;

    // stage x[b][c][n0+tok] -> lds[tok][c]; float4 over 4 consecutive tokens
    {
        int tk0 = (t & 7) * 4;
        int cb  = (t >> 3) * 8;
        const float* xb = x + ((size_t)b * C_ * N_) + n0 + tk0;
        float4 col[8];
        #pragma unroll
        for (int e = 0; e < 8; ++e)
            col[e] = *(const float4*)&xb[(size_t)(cb + e) * N_];
        #pragma unroll
        for (int tk = 0; tk < 4; ++tk) {
            u16x8 v;
            #pragma unroll
            for (int e = 0; e < 8; ++e) {
                float f = (tk == 0) ? col[e].x : (tk == 1) ? col[e].y
                        : (tk == 2) ? col[e].z : col[e].w;
                v[e] = f2bf(f);
            }
            *(u16x8*)&lds[(tk0 + tk) * K1_LDA + cb] = v;
        }
    }
    __syncthreads();

    // acc[0]=Q, acc[1]=K (swapped operands); acc[2]=V (original order)
    f32x4 acc[3][2][2];   // [tq][r2][nf]
    #pragma unroll
    for (int tq = 0; tq < 3; ++tq)
        #pragma unroll
        for (int r2 = 0; r2 < 2; ++r2)
            #pragma unroll
            for (int nf = 0; nf < 2; ++nf)
                acc[tq][r2][nf] = (f32x4){0.f, 0.f, 0.f, 0.f};

    const float* wsrc[3] = {wq, wk, wv};
    const int rbase = wv_ * 32;
    #pragma unroll
    for (int ks = 0; ks < 8; ++ks) {
        u16x8 a[2];
        #pragma unroll
        for (int nf = 0; nf < 2; ++nf)
            a[nf] = *(const u16x8*)&lds[(nf * 16 + q16) * K1_LDA + ks * 32 + g * 8];
        #pragma unroll
        for (int tq = 0; tq < 3; ++tq) {
            const float* w = wsrc[tq];
            #pragma unroll
            for (int r2 = 0; r2 < 2; ++r2) {
                u16x8 bf = ldw8(&w[(size_t)(rbase + r2 * 16 + q16) * 256 + ks * 32 + g * 8]);
                #pragma unroll
                for (int nf = 0; nf < 2; ++nf) {
                    if (tq < 2)
                        acc[tq][r2][nf] = mfma16(bf, a[nf], acc[tq][r2][nf]);  // swapped
                    else
                        acc[tq][r2][nf] = mfma16(a[nf], bf, acc[tq][r2][nf]);
                }
            }
        }
    }

    // Q (pre-scaled by SCALEL), K: fp8 e4m3 dword stores (4 consecutive r/thread)
    #pragma unroll
    for (int r2 = 0; r2 < 2; ++r2) {
        int rb = rbase + r2 * 16 + g * 4;
        float4 bq4 = *(const float4*)&bq[rb];
        float4 bk4 = *(const float4*)&bk[rb];
        #pragma unroll
        for (int nf = 0; nf < 2; ++nf) {
            int n = n0 + nf * 16 + q16;
            int qw32 = pk4fp8((acc[0][r2][nf][0] + bq4.x) * SCALEL,
                              (acc[0][r2][nf][1] + bq4.y) * SCALEL,
                              (acc[0][r2][nf][2] + bq4.z) * SCALEL,
                              (acc[0][r2][nf][3] + bq4.w) * SCALEL);
            int kw32 = pk4fp8(acc[1][r2][nf][0] + bk4.x, acc[1][r2][nf][1] + bk4.y,
                              acc[1][r2][nf][2] + bk4.z, acc[1][r2][nf][3] + bk4.w);
            size_t base = ((size_t)b * N_ + n) * RC_ + rb;
            *(unsigned int*)(Qf + base) = (unsigned int)qw32;
            *(unsigned int*)(Kf + base) = (unsigned int)kw32;
        }
    }

    // V: fp8 e4m3 image, stride 40 B per channel row; this block = one key-tile.
    const size_t tile = (size_t)b * 128 + blockIdx.x;
    #pragma unroll
    for (int r2 = 0; r2 < 2; ++r2) {
        int r = rbase + r2 * 16 + q16;
        float biasv = bv[r];
        #pragma unroll
        for (int nf = 0; nf < 2; ++nf) {
            int w = pk4fp8(acc[2][r2][nf][0] + biasv, acc[2][r2][nf][1] + biasv,
                           acc[2][r2][nf][2] + biasv, acc[2][r2][nf][3] + biasv);
            *(unsigned int*)(Vt8 + (tile * 128 + r) * 40 + g * 8 + nf * 4) = (unsigned int)w;
        }
    }
}

// ---------------- kernel 2: flash attention (fp8, double-buffered, 1 barrier/iter) ----------------
// 16 waves: qw = wv&1 (32 q-rows), grp = wv>>1 (512 keys, 16 tiles of 32).
// smem bytes: Q fp8 [0,8192) 64x128B XOR-swz;
//             K fp8 @8192+grp*8192 + p*4096: [32][128B] XOR-swz (DMA, dbuf);
//             V fp8 @73728+grp*10240 + p*5120: [128][40]B image (DMA, dbuf).
// merge overlay (post-loop): l f32 @ byte 0; U bf16 8x[64][132] @ byte 16384.
__global__ __launch_bounds__(1024, 4) void k_attn(
    const unsigned char* __restrict__ Qf, const unsigned char* __restrict__ Kf,
    const unsigned char* __restrict__ Vt8, unsigned short* __restrict__ Ob)
{
    __shared__ __align__(16) unsigned short smem[77824];   // 155648 B
    const int b  = blockIdx.y;
    const int n0 = blockIdx.x * 64;
    const int t  = threadIdx.x;
    const int lane = t & 63, wv_ = t >> 6;        // 16 waves
    const int qw = wv_ & 1, grp = wv_ >> 1;       // 8 KV groups
    const int g = lane >> 4, q16 = lane & 15;

    unsigned char* Ql8 = (unsigned char*)smem;                        // 8KB
    unsigned char* Klb = (unsigned char*)smem + 8192 + grp * 8192;    // 2x4KB
    unsigned char* Vlb = (unsigned char*)smem + 73728 + grp * 10240;  // 2x5KB

    const unsigned char* Qg = Qf + ((size_t)b * N_ + n0) * RC_;
    const unsigned char* Kg = Kf + ((size_t)b * N_ + grp * 512) * RC_;
    const unsigned char* Vg = Vt8 + ((size_t)b * 128 + grp * 16) * 5120;

    // ---- Q stage: 512 threads, 16B chunks, XOR-swizzled ds_write ----
    if (t < 512) {
        int row = t >> 3, ch = t & 7;
        uint4 v = *(const uint4*)&Qg[row * 128 + ch * 16];
        *(uint4*)&Ql8[row * 128 + ((ch ^ (row & 7)) * 16)] = v;
    }

    // ---- DMA staging into buffer pb_ ----
    #define STAGEK(kt_, pb_) do { int ktc = (kt_);                               \
        unsigned char* kdst = Klb + (pb_) * 4096;                                \
        _Pragma("unroll")                                                        \
        for (int r = 0; r < 2; ++r) {                                            \
            int id = (qw * 2 + r) * 64 + lane;   /* 0..255 chunks of 16B */      \
            int row = id >> 3, ch = id & 7;                                      \
            gl_lds16(Kg + (size_t)(ktc * 32 + row) * RC_ + ((ch ^ (row & 7)) * 16), \
                     kdst + (qw * 2 + r) * 1024);                                \
        }                                                                        \
    } while (0)
    #define STAGEV(kt_, pb_) do { int ktc = (kt_);                               \
        const char* vsrc = (const char*)(Vg + (size_t)ktc * 5120);               \
        char* vdst = (char*)(Vlb + (pb_) * 5120);                                \
        _Pragma("unroll")                                                        \
        for (int j = 0; j < 2; ++j) {                                            \
            int off = j * 2048 + qw * 1024;                                      \
            gl_lds16(vsrc + off + lane * 16, vdst + off);                        \
        }                                                                        \
        if (qw == 0)                                                             \
            gl_lds16(vsrc + 4096 + lane * 16, vdst + 4096);                      \
    } while (0)

    STAGEK(0, 0);
    STAGEV(0, 0);

    f32x4 acc_o[2][8];
    #pragma unroll
    for (int rf = 0; rf < 2; ++rf)
        #pragma unroll
        for (int df = 0; df < 8; ++df)
            acc_o[rf][df] = (f32x4){0.f, 0.f, 0.f, 0.f};
    float l_loc[2] = {0.f, 0.f};

    __syncthreads();   // Q ds_write + tile-0 DMA drained

    #pragma unroll 2
    for (int kt = 0; kt < 16; ++kt) {
        const int p = kt & 1;
        // prefetch tile kt+1 into the other buffer; full iteration to fly
        if (kt < 15) {
            STAGEK(kt + 1, p ^ 1);
            STAGEV(kt + 1, p ^ 1);
        }
        const unsigned char* Klp = Klb + p * 4096;
        const unsigned char* Vlp = Vlb + p * 5120;

        // S^T = K Q^T (swapped, fp8): lane holds S[q=qblock+q16][k=kf*16+g*4+i].
        f32x4 s[2][2];
        #pragma unroll
        for (int rf = 0; rf < 2; ++rf)
            #pragma unroll
            for (int kf = 0; kf < 2; ++kf)
                s[rf][kf] = (f32x4){0.f, 0.f, 0.f, 0.f};
        __builtin_amdgcn_s_setprio(1);
        #pragma unroll
        for (int ks = 0; ks < 4; ++ks) {
            int sw = (((2 * ks + (g >> 1)) ^ (q16 & 7)) * 16) + ((g & 1) * 8);
            long qv0 = *(const long*)&Ql8[(qw * 32 + q16) * 128 + sw];
            long qv1 = *(const long*)&Ql8[(qw * 32 + 16 + q16) * 128 + sw];
            #pragma unroll
            for (int kf = 0; kf < 2; ++kf) {
                long kv = *(const long*)&Klp[(kf * 16 + q16) * 128 + sw];
                s[0][kf] = __builtin_amdgcn_mfma_f32_16x16x32_fp8_fp8(kv, qv0, s[0][kf], 0, 0, 0);
                s[1][kf] = __builtin_amdgcn_mfma_f32_16x16x32_fp8_fp8(kv, qv1, s[1][kf], 0, 0, 0);
            }
        }
        __builtin_amdgcn_s_setprio(0);

        // no-max softmax: p = exp2(S) (SCALEL pre-folded into Q); pack P to fp8
        long pa8[2];
        #pragma unroll
        for (int rf = 0; rf < 2; ++rf) {
            #pragma unroll
            for (int kf = 0; kf < 2; ++kf)
                #pragma unroll
                for (int i = 0; i < 4; ++i)
                    s[rf][kf][i] = exp2f(s[rf][kf][i]);
            l_loc[rf] += (s[rf][0][0] + s[rf][0][1]) + (s[rf][0][2] + s[rf][0][3])
                       + (s[rf][1][0] + s[rf][1][1]) + (s[rf][1][2] + s[rf][1][3]);
            int2 pk2;
            pk2.x = pk4fp8(s[rf][0][0], s[rf][0][1], s[rf][0][2], s[rf][0][3]);
            pk2.y = pk4fp8(s[rf][1][0], s[rf][1][1], s[rf][1][2], s[rf][1][3]);
            pa8[rf] = __builtin_bit_cast(long, pk2);
        }

        // O += P @ V (fp8). V image row d: lane's 8 byte-slots at g*8 (one b64).
        __builtin_amdgcn_s_setprio(1);
        #pragma unroll
        for (int df = 0; df < 8; ++df) {
            int d = df * 16 + q16;
            long vv = *(const long*)&Vlp[d * 40 + g * 8];
            acc_o[0][df] = __builtin_amdgcn_mfma_f32_16x16x32_fp8_fp8(pa8[0], vv, acc_o[0][df], 0, 0, 0);
            acc_o[1][df] = __builtin_amdgcn_mfma_f32_16x16x32_fp8_fp8(pa8[1], vv, acc_o[1][df], 0, 0, 0);
        }
        __builtin_amdgcn_s_setprio(0);

        // single barrier: drains tile-(kt+1) DMA, fences reuse of buf[p] next+1
        __syncthreads();
    }

    // ---- merge across 8 KV groups (unchanged layout) ----
    float l0 = l_loc[0], l1 = l_loc[1];
    l0 += __shfl_xor(l0, 16); l0 += __shfl_xor(l0, 32);
    l1 += __shfl_xor(l1, 16); l1 += __shfl_xor(l1, 32);

    float* lf = (float*)smem;                       // [8 grp][64 rows]
    unsigned short* Ub = smem + 8192;               // [8 grp][64][132] bf16 @byte 16384
    if (g == 0) {
        lf[grp * 64 + qw * 32 + q16]      = l0;
        lf[grp * 64 + qw * 32 + 16 + q16] = l1;
    }
    {
        unsigned short* Ug = Ub + grp * 8448;
        #pragma unroll
        for (int rf = 0; rf < 2; ++rf)
            #pragma unroll
            for (int df = 0; df < 8; ++df)
                #pragma unroll
                for (int i = 0; i < 4; ++i)
                    Ug[(qw * 32 + rf * 16 + g * 4 + i) * 132 + df * 16 + q16] =
                        f2bf(acc_o[rf][df][i]);
    }
    __syncthreads();

    // combine: wave wv_ handles q-rows [wv_*4, wv_*4+4), lane covers 2 d-cols
    #pragma unroll
    for (int r = 0; r < 4; ++r) {
        int row = wv_ * 4 + r;
        float lt = 0.f;
        #pragma unroll
        for (int gg = 0; gg < 8; ++gg) lt += lf[gg * 64 + row];
        float inv = 1.f / lt;
        float o0 = 0.f, o1 = 0.f;
        #pragma unroll
        for (int gg = 0; gg < 8; ++gg) {
            unsigned int u = *(const unsigned int*)&Ub[gg * 8448 + row * 132 + lane * 2];
            o0 += __builtin_bit_cast(float, u << 16);
            o1 += __builtin_bit_cast(float, u & 0xffff0000u);
        }
        unsigned int packed = ((unsigned int)f2bf(o1 * inv) << 16) | f2bf(o0 * inv);
        *(unsigned int*)&Ob[((size_t)b * N_ + n0 + row) * RC_ + lane * 2] = packed;
    }
    #undef STAGEK
    #undef STAGEV
}

// ---------------- kernel 3: output projection + residual (round-10 verified) ----------------
#define QS 136  // 128 + 8 pad (shorts)

__global__ __launch_bounds__(256) void k_out(
    const unsigned short* __restrict__ Ob, const float* __restrict__ wo,
    const float* __restrict__ bo, const float* __restrict__ x,
    const float* __restrict__ gamma, float* __restrict__ out)
{
    __shared__ unsigned short Ol[64 * QS];
    const int b  = blockIdx.z;
    const int c0 = blockIdx.y * 64;
    const int n0 = blockIdx.x * 64;
    const int t  = threadIdx.x;
    const int lane = t & 63, wv_ = t >> 6;
    const int g = lane >> 4, q16 = lane & 15;

    {
        const unsigned short* src = Ob + ((size_t)b * N_ + n0) * RC_;
        #pragma unroll
        for (int p = 0; p < 4; ++p) {
            int row = p * 16 + (t >> 4);
            int s = (t & 15) * 8;
            *(u16x8*)&Ol[row * QS + s] = *(const u16x8*)&src[row * RC_ + s];
        }
    }
    __syncthreads();

    f32x4 acc[4];
    #pragma unroll
    for (int nf = 0; nf < 4; ++nf)
        acc[nf] = (f32x4){0.f, 0.f, 0.f, 0.f};

    const int cw = c0 + wv_ * 16;
    #pragma unroll
    for (int ks = 0; ks < 4; ++ks) {
        u16x8 b8[4];
        #pragma unroll
        for (int nf = 0; nf < 4; ++nf)
            b8[nf] = *(const u16x8*)&Ol[(nf * 16 + q16) * QS + ks * 32 + g * 8];
        u16x8 a8 = ldw8(&wo[(size_t)(cw + q16) * 128 + ks * 32 + g * 8]);
        #pragma unroll
        for (int nf = 0; nf < 4; ++nf)
            acc[nf] = mfma16(a8, b8[nf], acc[nf]);
    }

    float gm = gamma[0];
    #pragma unroll
    for (int i = 0; i < 4; ++i) {
        int c = cw + g * 4 + i;
        float bias = bo[c];
        #pragma unroll
        for (int nf = 0; nf < 4; ++nf) {
            int n = n0 + nf * 16 + q16;
            size_t idx = ((size_t)b * C_ + c) * N_ + n;
            out[idx] = gm * (acc[nf][i] + bias) + x[idx];
        }
    }
}

extern "C" void kernel_launch(void* const* d_in, const int* in_sizes, int n_in,
                              void* d_out, int out_size, void* d_ws, size_t ws_size,
                              hipStream_t stream) {
    const float* x     = (const float*)d_in[0];
    const float* wq    = (const float*)d_in[1];
    const float* bq    = (const float*)d_in[2];
    const float* wk    = (const float*)d_in[3];
    const float* bk    = (const float*)d_in[4];
    const float* wv    = (const float*)d_in[5];
    const float* bv    = (const float*)d_in[6];
    const float* wo    = (const float*)d_in[7];
    const float* bo    = (const float*)d_in[8];
    const float* gamma = (const float*)d_in[9];
    float* out = (float*)d_out;

    unsigned char* wsb = (unsigned char*)d_ws;
    unsigned char* Qf  = wsb;                               // [B][N][RC] fp8, 2MB
    unsigned char* Kf  = wsb + 2097152;                     // [B][N][RC] fp8, 2MB
    unsigned char* Vt8 = wsb + 4194304;                     // [B*128][128][40]B fp8 image, 2.62MB
    unsigned short* Ob = (unsigned short*)(wsb + 6815744);  // [B][N][RC] bf16, 4MB

    dim3 g1(128, 4);
    k_qkv<<<g1, 256, 0, stream>>>(x, wq, wk, wv, bq, bk, bv, Qf, Kf, Vt8);
    dim3 g2(64, 4);
    k_attn<<<g2, 1024, 0, stream>>>(Qf, Kf, Vt8, Ob);
    dim3 g3(64, 4, 4);
    k_out<<<g3, 256, 0, stream>>>(Ob, wo, bo, x, gamma, out);
}

// Round 18
// 73.999 us; speedup vs baseline: 1.3656x; 1.1004x over previous
//
#include <hip/hip_runtime.h>
#include <hip/hip_bf16.h>

// SelfAttentionBlock: B=4, C=256, RC=128, H=W=64 (N=4096)
// Round 18: k_qkv QBLK 32->64 (256 blocks). Each weight ldw8 now feeds 4 MFMAs
// (was 2); grid-total weight L2 traffic halves (196->98 MB) and cvt work halves.
// Store paths identical to round 16/17 (swapped Q/K fp8, SCALEL fold, fp8
// V-image with the round-8-verified tile/position formulas).
// k_attn (dbuf, 1 barrier/iter) and k_out identical to round 17 (81.4us).

#define B_   4
#define C_   256
#define RC_  128
#define N_   4096
#define SCALEL 0.12750880597462906f                // (1/sqrt(128)) * log2(e)

typedef __bf16 bf16x8 __attribute__((ext_vector_type(8)));
typedef unsigned short u16x8 __attribute__((ext_vector_type(8)));
typedef float f32x4 __attribute__((ext_vector_type(4)));

static __device__ __forceinline__ unsigned short f2bf(float f) {
    unsigned int u = __builtin_bit_cast(unsigned int, f);
    u += 0x7fffu + ((u >> 16) & 1u);
    return (unsigned short)(u >> 16);
}

static __device__ __forceinline__ f32x4 mfma16(u16x8 a, u16x8 b, f32x4 c) {
    return __builtin_amdgcn_mfma_f32_16x16x32_bf16(
        __builtin_bit_cast(bf16x8, a), __builtin_bit_cast(bf16x8, b), c, 0, 0, 0);
}

static __device__ __forceinline__ unsigned int cvtpk(float lo, float hi) {
    unsigned int r;
    asm("v_cvt_pk_bf16_f32 %0, %1, %2" : "=v"(r) : "v"(lo), "v"(hi));
    return r;   // low 16 = bf16(lo), high 16 = bf16(hi), RNE
}

// load 8 consecutive f32 weights and pack to bf16x8 (same RNE as f2bf)
static __device__ __forceinline__ u16x8 ldw8(const float* p) {
    float4 f0 = *(const float4*)p;
    float4 f1 = *(const float4*)(p + 4);
    int4 pk;
    pk.x = (int)cvtpk(f0.x, f0.y);
    pk.y = (int)cvtpk(f0.z, f0.w);
    pk.z = (int)cvtpk(f1.x, f1.y);
    pk.w = (int)cvtpk(f1.z, f1.w);
    return __builtin_bit_cast(u16x8, pk);
}

// pack 4 f32 -> 4 fp8 e4m3 bytes
static __device__ __forceinline__ int pk4fp8(float a, float b, float c, float d) {
    int w = __builtin_amdgcn_cvt_pk_fp8_f32(a, b, 0, false);
    w = __builtin_amdgcn_cvt_pk_fp8_f32(c, d, w, true);
    return w;
}

static __device__ __forceinline__ void gl_lds16(const void* g, void* l) {
    __builtin_amdgcn_global_load_lds(
        (const __attribute__((address_space(1))) void*)g,
        (__attribute__((address_space(3))) void*)l, 16, 0, 0);
}

// ---------------- kernel 1: QKV projection (QBLK=64; fp8 Q/K/V out) ----------------
#define K1_LDA 264  // 256 + 8 pad (shorts)

__global__ __launch_bounds__(256) void k_qkv(
    const float* __restrict__ x,
    const float* __restrict__ wq, const float* __restrict__ wk, const float* __restrict__ wv,
    const float* __restrict__ bq, const float* __restrict__ bk, const float* __restrict__ bv,
    unsigned char* __restrict__ Qf, unsigned char* __restrict__ Kf,
    unsigned char* __restrict__ Vt8)
{
    __shared__ unsigned short lds[64 * K1_LDA];   // 33.8 K shorts = 67.6 KB
    const int b  = blockIdx.y;
    const int n0 = blockIdx.x * 64;
    const int t  = threadIdx.x;
    const int lane = t & 63, wv_ = t >> 6;
    const int g = lane >> 4, q16 = lane & 15;

    // stage x[b][c][n0+tok] -> lds[tok][c]; thread covers 4 consecutive tokens
    // x 16 channels via float4 loads (lanes 0..15 cover one full 256B token-row).
    {
        int tk0 = (t & 15) * 4;                   // 4 consecutive tokens
        int cb  = (t >> 4) * 16;                  // 16 channels
        const float* xb = x + ((size_t)b * C_ * N_) + n0 + tk0;
        float4 col[16];
        #pragma unroll
        for (int e = 0; e < 16; ++e)
            col[e] = *(const float4*)&xb[(size_t)(cb + e) * N_];
        #pragma unroll
        for (int tk = 0; tk < 4; ++tk) {
            #pragma unroll
            for (int h = 0; h < 2; ++h) {
                u16x8 v;
                #pragma unroll
                for (int e = 0; e < 8; ++e) {
                    float f = (tk == 0) ? col[h * 8 + e].x : (tk == 1) ? col[h * 8 + e].y
                            : (tk == 2) ? col[h * 8 + e].z : col[h * 8 + e].w;
                    v[e] = f2bf(f);
                }
                *(u16x8*)&lds[(tk0 + tk) * K1_LDA + cb + h * 8] = v;
            }
        }
    }
    __syncthreads();

    // acc[0]=Q, acc[1]=K (swapped operands: thread holds r = rbase+r2*16+g*4+i,
    //                     n = n0+nf*16+q16)
    // acc[2]=V (original order: thread holds r = rbase+r2*16+q16,
    //                     n = n0+nf*16+g*4+i)
    f32x4 acc[3][2][4];   // [tq][r2][nf]
    #pragma unroll
    for (int tq = 0; tq < 3; ++tq)
        #pragma unroll
        for (int r2 = 0; r2 < 2; ++r2)
            #pragma unroll
            for (int nf = 0; nf < 4; ++nf)
                acc[tq][r2][nf] = (f32x4){0.f, 0.f, 0.f, 0.f};

    const float* wsrc[3] = {wq, wk, wv};
    const int rbase = wv_ * 32;
    #pragma unroll
    for (int ks = 0; ks < 8; ++ks) {
        u16x8 a[4];
        #pragma unroll
        for (int nf = 0; nf < 4; ++nf)
            a[nf] = *(const u16x8*)&lds[(nf * 16 + q16) * K1_LDA + ks * 32 + g * 8];
        #pragma unroll
        for (int tq = 0; tq < 3; ++tq) {
            const float* w = wsrc[tq];
            #pragma unroll
            for (int r2 = 0; r2 < 2; ++r2) {
                u16x8 bf = ldw8(&w[(size_t)(rbase + r2 * 16 + q16) * 256 + ks * 32 + g * 8]);
                #pragma unroll
                for (int nf = 0; nf < 4; ++nf) {
                    if (tq < 2)
                        acc[tq][r2][nf] = mfma16(bf, a[nf], acc[tq][r2][nf]);  // swapped
                    else
                        acc[tq][r2][nf] = mfma16(a[nf], bf, acc[tq][r2][nf]);
                }
            }
        }
    }

    // Q (pre-scaled by SCALEL), K: fp8 e4m3 dword stores (4 consecutive r/thread)
    #pragma unroll
    for (int r2 = 0; r2 < 2; ++r2) {
        int rb = rbase + r2 * 16 + g * 4;
        float4 bq4 = *(const float4*)&bq[rb];
        float4 bk4 = *(const float4*)&bk[rb];
        #pragma unroll
        for (int nf = 0; nf < 4; ++nf) {
            int n = n0 + nf * 16 + q16;
            int qw32 = pk4fp8((acc[0][r2][nf][0] + bq4.x) * SCALEL,
                              (acc[0][r2][nf][1] + bq4.y) * SCALEL,
                              (acc[0][r2][nf][2] + bq4.z) * SCALEL,
                              (acc[0][r2][nf][3] + bq4.w) * SCALEL);
            int kw32 = pk4fp8(acc[1][r2][nf][0] + bk4.x, acc[1][r2][nf][1] + bk4.y,
                              acc[1][r2][nf][2] + bk4.z, acc[1][r2][nf][3] + bk4.w);
            size_t base = ((size_t)b * N_ + n) * RC_ + rb;
            *(unsigned int*)(Qf + base) = (unsigned int)qw32;
            *(unsigned int*)(Kf + base) = (unsigned int)kw32;
        }
    }

    // V: fp8 e4m3 image, stride 40 B per channel row.
    // tile = b*128 + (n0>>5) + (nf>>1); key k = (nf&1)*16 + g*4 + i
    // -> byte position p = g*8 + (nf&1)*4 + i  (round-8-verified mapping).
    #pragma unroll
    for (int r2 = 0; r2 < 2; ++r2) {
        int r = rbase + r2 * 16 + q16;
        float biasv = bv[r];
        #pragma unroll
        for (int nf = 0; nf < 4; ++nf) {
            int w = pk4fp8(acc[2][r2][nf][0] + biasv, acc[2][r2][nf][1] + biasv,
                           acc[2][r2][nf][2] + biasv, acc[2][r2][nf][3] + biasv);
            size_t tile = (size_t)b * 128 + (n0 >> 5) + (nf >> 1);
            *(unsigned int*)(Vt8 + (tile * 128 + r) * 40 + g * 8 + (nf & 1) * 4) = (unsigned int)w;
        }
    }
}

// ---------------- kernel 2: flash attention (fp8, double-buffered, 1 barrier/iter) ----------------
// 16 waves: qw = wv&1 (32 q-rows), grp = wv>>1 (512 keys, 16 tiles of 32).
// smem bytes: Q fp8 [0,8192) 64x128B XOR-swz;
//             K fp8 @8192+grp*8192 + p*4096: [32][128B] XOR-swz (DMA, dbuf);
//             V fp8 @73728+grp*10240 + p*5120: [128][40]B image (DMA, dbuf).
// merge overlay (post-loop): l f32 @ byte 0; U bf16 8x[64][132] @ byte 16384.
__global__ __launch_bounds__(1024, 4) void k_attn(
    const unsigned char* __restrict__ Qf, const unsigned char* __restrict__ Kf,
    const unsigned char* __restrict__ Vt8, unsigned short* __restrict__ Ob)
{
    __shared__ __align__(16) unsigned short smem[77824];   // 155648 B
    const int b  = blockIdx.y;
    const int n0 = blockIdx.x * 64;
    const int t  = threadIdx.x;
    const int lane = t & 63, wv_ = t >> 6;        // 16 waves
    const int qw = wv_ & 1, grp = wv_ >> 1;       // 8 KV groups
    const int g = lane >> 4, q16 = lane & 15;

    unsigned char* Ql8 = (unsigned char*)smem;                        // 8KB
    unsigned char* Klb = (unsigned char*)smem + 8192 + grp * 8192;    // 2x4KB
    unsigned char* Vlb = (unsigned char*)smem + 73728 + grp * 10240;  // 2x5KB

    const unsigned char* Qg = Qf + ((size_t)b * N_ + n0) * RC_;
    const unsigned char* Kg = Kf + ((size_t)b * N_ + grp * 512) * RC_;
    const unsigned char* Vg = Vt8 + ((size_t)b * 128 + grp * 16) * 5120;

    // ---- Q stage: 512 threads, 16B chunks, XOR-swizzled ds_write ----
    if (t < 512) {
        int row = t >> 3, ch = t & 7;
        uint4 v = *(const uint4*)&Qg[row * 128 + ch * 16];
        *(uint4*)&Ql8[row * 128 + ((ch ^ (row & 7)) * 16)] = v;
    }

    // ---- DMA staging into buffer pb_ ----
    #define STAGEK(kt_, pb_) do { int ktc = (kt_);                               \
        unsigned char* kdst = Klb + (pb_) * 4096;                                \
        _Pragma("unroll")                                                        \
        for (int r = 0; r < 2; ++r) {                                            \
            int id = (qw * 2 + r) * 64 + lane;   /* 0..255 chunks of 16B */      \
            int row = id >> 3, ch = id & 7;                                      \
            gl_lds16(Kg + (size_t)(ktc * 32 + row) * RC_ + ((ch ^ (row & 7)) * 16), \
                     kdst + (qw * 2 + r) * 1024);                                \
        }                                                                        \
    } while (0)
    #define STAGEV(kt_, pb_) do { int ktc = (kt_);                               \
        const char* vsrc = (const char*)(Vg + (size_t)ktc * 5120);               \
        char* vdst = (char*)(Vlb + (pb_) * 5120);                                \
        _Pragma("unroll")                                                        \
        for (int j = 0; j < 2; ++j) {                                            \
            int off = j * 2048 + qw * 1024;                                      \
            gl_lds16(vsrc + off + lane * 16, vdst + off);                        \
        }                                                                        \
        if (qw == 0)                                                             \
            gl_lds16(vsrc + 4096 + lane * 16, vdst + 4096);                      \
    } while (0)

    STAGEK(0, 0);
    STAGEV(0, 0);

    f32x4 acc_o[2][8];
    #pragma unroll
    for (int rf = 0; rf < 2; ++rf)
        #pragma unroll
        for (int df = 0; df < 8; ++df)
            acc_o[rf][df] = (f32x4){0.f, 0.f, 0.f, 0.f};
    float l_loc[2] = {0.f, 0.f};

    __syncthreads();   // Q ds_write + tile-0 DMA drained

    #pragma unroll 2
    for (int kt = 0; kt < 16; ++kt) {
        const int p = kt & 1;
        // prefetch tile kt+1 into the other buffer; full iteration to fly
        if (kt < 15) {
            STAGEK(kt + 1, p ^ 1);
            STAGEV(kt + 1, p ^ 1);
        }
        const unsigned char* Klp = Klb + p * 4096;
        const unsigned char* Vlp = Vlb + p * 5120;

        // S^T = K Q^T (swapped, fp8): lane holds S[q=qblock+q16][k=kf*16+g*4+i].
        f32x4 s[2][2];
        #pragma unroll
        for (int rf = 0; rf < 2; ++rf)
            #pragma unroll
            for (int kf = 0; kf < 2; ++kf)
                s[rf][kf] = (f32x4){0.f, 0.f, 0.f, 0.f};
        __builtin_amdgcn_s_setprio(1);
        #pragma unroll
        for (int ks = 0; ks < 4; ++ks) {
            int sw = (((2 * ks + (g >> 1)) ^ (q16 & 7)) * 16) + ((g & 1) * 8);
            long qv0 = *(const long*)&Ql8[(qw * 32 + q16) * 128 + sw];
            long qv1 = *(const long*)&Ql8[(qw * 32 + 16 + q16) * 128 + sw];
            #pragma unroll
            for (int kf = 0; kf < 2; ++kf) {
                long kv = *(const long*)&Klp[(kf * 16 + q16) * 128 + sw];
                s[0][kf] = __builtin_amdgcn_mfma_f32_16x16x32_fp8_fp8(kv, qv0, s[0][kf], 0, 0, 0);
                s[1][kf] = __builtin_amdgcn_mfma_f32_16x16x32_fp8_fp8(kv, qv1, s[1][kf], 0, 0, 0);
            }
        }
        __builtin_amdgcn_s_setprio(0);

        // no-max softmax: p = exp2(S) (SCALEL pre-folded into Q); pack P to fp8
        long pa8[2];
        #pragma unroll
        for (int rf = 0; rf < 2; ++rf) {
            #pragma unroll
            for (int kf = 0; kf < 2; ++kf)
                #pragma unroll
                for (int i = 0; i < 4; ++i)
                    s[rf][kf][i] = exp2f(s[rf][kf][i]);
            l_loc[rf] += (s[rf][0][0] + s[rf][0][1]) + (s[rf][0][2] + s[rf][0][3])
                       + (s[rf][1][0] + s[rf][1][1]) + (s[rf][1][2] + s[rf][1][3]);
            int2 pk2;
            pk2.x = pk4fp8(s[rf][0][0], s[rf][0][1], s[rf][0][2], s[rf][0][3]);
            pk2.y = pk4fp8(s[rf][1][0], s[rf][1][1], s[rf][1][2], s[rf][1][3]);
            pa8[rf] = __builtin_bit_cast(long, pk2);
        }

        // O += P @ V (fp8). V image row d: lane's 8 byte-slots at g*8 (one b64).
        __builtin_amdgcn_s_setprio(1);
        #pragma unroll
        for (int df = 0; df < 8; ++df) {
            int d = df * 16 + q16;
            long vv = *(const long*)&Vlp[d * 40 + g * 8];
            acc_o[0][df] = __builtin_amdgcn_mfma_f32_16x16x32_fp8_fp8(pa8[0], vv, acc_o[0][df], 0, 0, 0);
            acc_o[1][df] = __builtin_amdgcn_mfma_f32_16x16x32_fp8_fp8(pa8[1], vv, acc_o[1][df], 0, 0, 0);
        }
        __builtin_amdgcn_s_setprio(0);

        // single barrier: drains tile-(kt+1) DMA, fences reuse of buf[p]
        __syncthreads();
    }

    // ---- merge across 8 KV groups (unchanged layout) ----
    float l0 = l_loc[0], l1 = l_loc[1];
    l0 += __shfl_xor(l0, 16); l0 += __shfl_xor(l0, 32);
    l1 += __shfl_xor(l1, 16); l1 += __shfl_xor(l1, 32);

    float* lf = (float*)smem;                       // [8 grp][64 rows]
    unsigned short* Ub = smem + 8192;               // [8 grp][64][132] bf16 @byte 16384
    if (g == 0) {
        lf[grp * 64 + qw * 32 + q16]      = l0;
        lf[grp * 64 + qw * 32 + 16 + q16] = l1;
    }
    {
        unsigned short* Ug = Ub + grp * 8448;
        #pragma unroll
        for (int rf = 0; rf < 2; ++rf)
            #pragma unroll
            for (int df = 0; df < 8; ++df)
                #pragma unroll
                for (int i = 0; i < 4; ++i)
                    Ug[(qw * 32 + rf * 16 + g * 4 + i) * 132 + df * 16 + q16] =
                        f2bf(acc_o[rf][df][i]);
    }
    __syncthreads();

    // combine: wave wv_ handles q-rows [wv_*4, wv_*4+4), lane covers 2 d-cols
    #pragma unroll
    for (int r = 0; r < 4; ++r) {
        int row = wv_ * 4 + r;
        float lt = 0.f;
        #pragma unroll
        for (int gg = 0; gg < 8; ++gg) lt += lf[gg * 64 + row];
        float inv = 1.f / lt;
        float o0 = 0.f, o1 = 0.f;
        #pragma unroll
        for (int gg = 0; gg < 8; ++gg) {
            unsigned int u = *(const unsigned int*)&Ub[gg * 8448 + row * 132 + lane * 2];
            o0 += __builtin_bit_cast(float, u << 16);
            o1 += __builtin_bit_cast(float, u & 0xffff0000u);
        }
        unsigned int packed = ((unsigned int)f2bf(o1 * inv) << 16) | f2bf(o0 * inv);
        *(unsigned int*)&Ob[((size_t)b * N_ + n0 + row) * RC_ + lane * 2] = packed;
    }
    #undef STAGEK
    #undef STAGEV
}

// ---------------- kernel 3: output projection + residual (round-10 verified) ----------------
#define QS 136  // 128 + 8 pad (shorts)

__global__ __launch_bounds__(256) void k_out(
    const unsigned short* __restrict__ Ob, const float* __restrict__ wo,
    const float* __restrict__ bo, const float* __restrict__ x,
    const float* __restrict__ gamma, float* __restrict__ out)
{
    __shared__ unsigned short Ol[64 * QS];
    const int b  = blockIdx.z;
    const int c0 = blockIdx.y * 64;
    const int n0 = blockIdx.x * 64;
    const int t  = threadIdx.x;
    const int lane = t & 63, wv_ = t >> 6;
    const int g = lane >> 4, q16 = lane & 15;

    {
        const unsigned short* src = Ob + ((size_t)b * N_ + n0) * RC_;
        #pragma unroll
        for (int p = 0; p < 4; ++p) {
            int row = p * 16 + (t >> 4);
            int s = (t & 15) * 8;
            *(u16x8*)&Ol[row * QS + s] = *(const u16x8*)&src[row * RC_ + s];
        }
    }
    __syncthreads();

    f32x4 acc[4];
    #pragma unroll
    for (int nf = 0; nf < 4; ++nf)
        acc[nf] = (f32x4){0.f, 0.f, 0.f, 0.f};

    const int cw = c0 + wv_ * 16;
    #pragma unroll
    for (int ks = 0; ks < 4; ++ks) {
        u16x8 b8[4];
        #pragma unroll
        for (int nf = 0; nf < 4; ++nf)
            b8[nf] = *(const u16x8*)&Ol[(nf * 16 + q16) * QS + ks * 32 + g * 8];
        u16x8 a8 = ldw8(&wo[(size_t)(cw + q16) * 128 + ks * 32 + g * 8]);
        #pragma unroll
        for (int nf = 0; nf < 4; ++nf)
            acc[nf] = mfma16(a8, b8[nf], acc[nf]);
    }

    float gm = gamma[0];
    #pragma unroll
    for (int i = 0; i < 4; ++i) {
        int c = cw + g * 4 + i;
        float bias = bo[c];
        #pragma unroll
        for (int nf = 0; nf < 4; ++nf) {
            int n = n0 + nf * 16 + q16;
            size_t idx = ((size_t)b * C_ + c) * N_ + n;
            out[idx] = gm * (acc[nf][i] + bias) + x[idx];
        }
    }
}

extern "C" void kernel_launch(void* const* d_in, const int* in_sizes, int n_in,
                              void* d_out, int out_size, void* d_ws, size_t ws_size,
                              hipStream_t stream) {
    const float* x     = (const float*)d_in[0];
    const float* wq    = (const float*)d_in[1];
    const float* bq    = (const float*)d_in[2];
    const float* wk    = (const float*)d_in[3];
    const float* bk    = (const float*)d_in[4];
    const float* wv    = (const float*)d_in[5];
    const float* bv    = (const float*)d_in[6];
    const float* wo    = (const float*)d_in[7];
    const float* bo    = (const float*)d_in[8];
    const float* gamma = (const float*)d_in[9];
    float* out = (float*)d_out;

    unsigned char* wsb = (unsigned char*)d_ws;
    unsigned char* Qf  = wsb;                               // [B][N][RC] fp8, 2MB
    unsigned char* Kf  = wsb + 2097152;                     // [B][N][RC] fp8, 2MB
    unsigned char* Vt8 = wsb + 4194304;                     // [B*128][128][40]B fp8 image, 2.62MB
    unsigned short* Ob = (unsigned short*)(wsb + 6815744);  // [B][N][RC] bf16, 4MB

    dim3 g1(64, 4);
    k_qkv<<<g1, 256, 0, stream>>>(x, wq, wk, wv, bq, bk, bv, Qf, Kf, Vt8);
    dim3 g2(64, 4);
    k_attn<<<g2, 1024, 0, stream>>>(Qf, Kf, Vt8, Ob);
    dim3 g3(64, 4, 4);
    k_out<<<g3, 256, 0, stream>>>(Ob, wo, bo, x, gamma, out);
}

// Round 19
// 73.425 us; speedup vs baseline: 1.3763x; 1.0078x over previous
//
#include <hip/hip_runtime.h>
#include <hip/hip_bf16.h>

// SelfAttentionBlock: B=4, C=256, RC=128, H=W=64 (N=4096)
// Round 19 (on round-18 verified base, 74.0us):
//  (1) k_out NBLK 64->128 (grid 512): each wo ldw8 feeds 8 MFMAs (was 4);
//      grid-total wo L2 traffic halves. Same verified fragment mappings.
//  (2) k_attn Q-stage via global_load_lds (linear dest = t*16 per wave;
//      XOR swizzle moved to the per-lane SOURCE address).
// k_qkv identical to round 18; k_attn loop/merge identical to round 17/18.

#define B_   4
#define C_   256
#define RC_  128
#define N_   4096
#define SCALEL 0.12750880597462906f                // (1/sqrt(128)) * log2(e)

typedef __bf16 bf16x8 __attribute__((ext_vector_type(8)));
typedef unsigned short u16x8 __attribute__((ext_vector_type(8)));
typedef float f32x4 __attribute__((ext_vector_type(4)));

static __device__ __forceinline__ unsigned short f2bf(float f) {
    unsigned int u = __builtin_bit_cast(unsigned int, f);
    u += 0x7fffu + ((u >> 16) & 1u);
    return (unsigned short)(u >> 16);
}

static __device__ __forceinline__ f32x4 mfma16(u16x8 a, u16x8 b, f32x4 c) {
    return __builtin_amdgcn_mfma_f32_16x16x32_bf16(
        __builtin_bit_cast(bf16x8, a), __builtin_bit_cast(bf16x8, b), c, 0, 0, 0);
}

static __device__ __forceinline__ unsigned int cvtpk(float lo, float hi) {
    unsigned int r;
    asm("v_cvt_pk_bf16_f32 %0, %1, %2" : "=v"(r) : "v"(lo), "v"(hi));
    return r;   // low 16 = bf16(lo), high 16 = bf16(hi), RNE
}

// load 8 consecutive f32 weights and pack to bf16x8 (same RNE as f2bf)
static __device__ __forceinline__ u16x8 ldw8(const float* p) {
    float4 f0 = *(const float4*)p;
    float4 f1 = *(const float4*)(p + 4);
    int4 pk;
    pk.x = (int)cvtpk(f0.x, f0.y);
    pk.y = (int)cvtpk(f0.z, f0.w);
    pk.z = (int)cvtpk(f1.x, f1.y);
    pk.w = (int)cvtpk(f1.z, f1.w);
    return __builtin_bit_cast(u16x8, pk);
}

// pack 4 f32 -> 4 fp8 e4m3 bytes
static __device__ __forceinline__ int pk4fp8(float a, float b, float c, float d) {
    int w = __builtin_amdgcn_cvt_pk_fp8_f32(a, b, 0, false);
    w = __builtin_amdgcn_cvt_pk_fp8_f32(c, d, w, true);
    return w;
}

static __device__ __forceinline__ void gl_lds16(const void* g, void* l) {
    __builtin_amdgcn_global_load_lds(
        (const __attribute__((address_space(1))) void*)g,
        (__attribute__((address_space(3))) void*)l, 16, 0, 0);
}

// ---------------- kernel 1: QKV projection (QBLK=64; round-18 verified) ----------------
#define K1_LDA 264  // 256 + 8 pad (shorts)

__global__ __launch_bounds__(256) void k_qkv(
    const float* __restrict__ x,
    const float* __restrict__ wq, const float* __restrict__ wk, const float* __restrict__ wv,
    const float* __restrict__ bq, const float* __restrict__ bk, const float* __restrict__ bv,
    unsigned char* __restrict__ Qf, unsigned char* __restrict__ Kf,
    unsigned char* __restrict__ Vt8)
{
    __shared__ unsigned short lds[64 * K1_LDA];   // 67.6 KB
    const int b  = blockIdx.y;
    const int n0 = blockIdx.x * 64;
    const int t  = threadIdx.x;
    const int lane = t & 63, wv_ = t >> 6;
    const int g = lane >> 4, q16 = lane & 15;

    // stage x[b][c][n0+tok] -> lds[tok][c]; 4 consecutive tokens x 16 channels
    {
        int tk0 = (t & 15) * 4;
        int cb  = (t >> 4) * 16;
        const float* xb = x + ((size_t)b * C_ * N_) + n0 + tk0;
        float4 col[16];
        #pragma unroll
        for (int e = 0; e < 16; ++e)
            col[e] = *(const float4*)&xb[(size_t)(cb + e) * N_];
        #pragma unroll
        for (int tk = 0; tk < 4; ++tk) {
            #pragma unroll
            for (int h = 0; h < 2; ++h) {
                u16x8 v;
                #pragma unroll
                for (int e = 0; e < 8; ++e) {
                    float f = (tk == 0) ? col[h * 8 + e].x : (tk == 1) ? col[h * 8 + e].y
                            : (tk == 2) ? col[h * 8 + e].z : col[h * 8 + e].w;
                    v[e] = f2bf(f);
                }
                *(u16x8*)&lds[(tk0 + tk) * K1_LDA + cb + h * 8] = v;
            }
        }
    }
    __syncthreads();

    f32x4 acc[3][2][4];   // [tq][r2][nf]
    #pragma unroll
    for (int tq = 0; tq < 3; ++tq)
        #pragma unroll
        for (int r2 = 0; r2 < 2; ++r2)
            #pragma unroll
            for (int nf = 0; nf < 4; ++nf)
                acc[tq][r2][nf] = (f32x4){0.f, 0.f, 0.f, 0.f};

    const float* wsrc[3] = {wq, wk, wv};
    const int rbase = wv_ * 32;
    #pragma unroll
    for (int ks = 0; ks < 8; ++ks) {
        u16x8 a[4];
        #pragma unroll
        for (int nf = 0; nf < 4; ++nf)
            a[nf] = *(const u16x8*)&lds[(nf * 16 + q16) * K1_LDA + ks * 32 + g * 8];
        #pragma unroll
        for (int tq = 0; tq < 3; ++tq) {
            const float* w = wsrc[tq];
            #pragma unroll
            for (int r2 = 0; r2 < 2; ++r2) {
                u16x8 bf = ldw8(&w[(size_t)(rbase + r2 * 16 + q16) * 256 + ks * 32 + g * 8]);
                #pragma unroll
                for (int nf = 0; nf < 4; ++nf) {
                    if (tq < 2)
                        acc[tq][r2][nf] = mfma16(bf, a[nf], acc[tq][r2][nf]);  // swapped
                    else
                        acc[tq][r2][nf] = mfma16(a[nf], bf, acc[tq][r2][nf]);
                }
            }
        }
    }

    // Q (pre-scaled by SCALEL), K: fp8 e4m3 dword stores (4 consecutive r/thread)
    #pragma unroll
    for (int r2 = 0; r2 < 2; ++r2) {
        int rb = rbase + r2 * 16 + g * 4;
        float4 bq4 = *(const float4*)&bq[rb];
        float4 bk4 = *(const float4*)&bk[rb];
        #pragma unroll
        for (int nf = 0; nf < 4; ++nf) {
            int n = n0 + nf * 16 + q16;
            int qw32 = pk4fp8((acc[0][r2][nf][0] + bq4.x) * SCALEL,
                              (acc[0][r2][nf][1] + bq4.y) * SCALEL,
                              (acc[0][r2][nf][2] + bq4.z) * SCALEL,
                              (acc[0][r2][nf][3] + bq4.w) * SCALEL);
            int kw32 = pk4fp8(acc[1][r2][nf][0] + bk4.x, acc[1][r2][nf][1] + bk4.y,
                              acc[1][r2][nf][2] + bk4.z, acc[1][r2][nf][3] + bk4.w);
            size_t base = ((size_t)b * N_ + n) * RC_ + rb;
            *(unsigned int*)(Qf + base) = (unsigned int)qw32;
            *(unsigned int*)(Kf + base) = (unsigned int)kw32;
        }
    }

    // V: fp8 e4m3 image, stride 40 B per channel row (round-8-verified mapping).
    #pragma unroll
    for (int r2 = 0; r2 < 2; ++r2) {
        int r = rbase + r2 * 16 + q16;
        float biasv = bv[r];
        #pragma unroll
        for (int nf = 0; nf < 4; ++nf) {
            int w = pk4fp8(acc[2][r2][nf][0] + biasv, acc[2][r2][nf][1] + biasv,
                           acc[2][r2][nf][2] + biasv, acc[2][r2][nf][3] + biasv);
            size_t tile = (size_t)b * 128 + (n0 >> 5) + (nf >> 1);
            *(unsigned int*)(Vt8 + (tile * 128 + r) * 40 + g * 8 + (nf & 1) * 4) = (unsigned int)w;
        }
    }
}

// ---------------- kernel 2: flash attention (fp8, dbuf, 1 barrier/iter) ----------------
// 16 waves: qw = wv&1 (32 q-rows), grp = wv>>1 (512 keys, 16 tiles of 32).
// smem bytes: Q fp8 [0,8192) 64x128B XOR-swz (DMA, source-swizzled);
//             K fp8 @8192+grp*8192 + p*4096: [32][128B] XOR-swz (DMA, dbuf);
//             V fp8 @73728+grp*10240 + p*5120: [128][40]B image (DMA, dbuf).
// merge overlay (post-loop): l f32 @ byte 0; U bf16 8x[64][132] @ byte 16384.
__global__ __launch_bounds__(1024, 4) void k_attn(
    const unsigned char* __restrict__ Qf, const unsigned char* __restrict__ Kf,
    const unsigned char* __restrict__ Vt8, unsigned short* __restrict__ Ob)
{
    __shared__ __align__(16) unsigned short smem[77824];   // 155648 B
    const int b  = blockIdx.y;
    const int n0 = blockIdx.x * 64;
    const int t  = threadIdx.x;
    const int lane = t & 63, wv_ = t >> 6;        // 16 waves
    const int qw = wv_ & 1, grp = wv_ >> 1;       // 8 KV groups
    const int g = lane >> 4, q16 = lane & 15;

    unsigned char* Ql8 = (unsigned char*)smem;                        // 8KB
    unsigned char* Klb = (unsigned char*)smem + 8192 + grp * 8192;    // 2x4KB
    unsigned char* Vlb = (unsigned char*)smem + 73728 + grp * 10240;  // 2x5KB

    const unsigned char* Qg = Qf + ((size_t)b * N_ + n0) * RC_;
    const unsigned char* Kg = Kf + ((size_t)b * N_ + grp * 512) * RC_;
    const unsigned char* Vg = Vt8 + ((size_t)b * 128 + grp * 16) * 5120;

    // ---- Q stage via DMA: linear dest (byte t*16 within wave), swizzled source ----
    if (t < 512) {
        int row = t >> 3, ch = (t & 7) ^ (row & 7);
        gl_lds16(Qg + row * 128 + ch * 16, (char*)Ql8 + wv_ * 1024);
    }

    // ---- DMA staging into buffer pb_ ----
    #define STAGEK(kt_, pb_) do { int ktc = (kt_);                               \
        unsigned char* kdst = Klb + (pb_) * 4096;                                \
        _Pragma("unroll")                                                        \
        for (int r = 0; r < 2; ++r) {                                            \
            int id = (qw * 2 + r) * 64 + lane;   /* 0..255 chunks of 16B */      \
            int row = id >> 3, ch = id & 7;                                      \
            gl_lds16(Kg + (size_t)(ktc * 32 + row) * RC_ + ((ch ^ (row & 7)) * 16), \
                     kdst + (qw * 2 + r) * 1024);                                \
        }                                                                        \
    } while (0)
    #define STAGEV(kt_, pb_) do { int ktc = (kt_);                               \
        const char* vsrc = (const char*)(Vg + (size_t)ktc * 5120);               \
        char* vdst = (char*)(Vlb + (pb_) * 5120);                                \
        _Pragma("unroll")                                                        \
        for (int j = 0; j < 2; ++j) {                                            \
            int off = j * 2048 + qw * 1024;                                      \
            gl_lds16(vsrc + off + lane * 16, vdst + off);                        \
        }                                                                        \
        if (qw == 0)                                                             \
            gl_lds16(vsrc + 4096 + lane * 16, vdst + 4096);                      \
    } while (0)

    STAGEK(0, 0);
    STAGEV(0, 0);

    f32x4 acc_o[2][8];
    #pragma unroll
    for (int rf = 0; rf < 2; ++rf)
        #pragma unroll
        for (int df = 0; df < 8; ++df)
            acc_o[rf][df] = (f32x4){0.f, 0.f, 0.f, 0.f};
    float l_loc[2] = {0.f, 0.f};

    __syncthreads();   // Q + tile-0 DMA drained

    #pragma unroll 2
    for (int kt = 0; kt < 16; ++kt) {
        const int p = kt & 1;
        if (kt < 15) {
            STAGEK(kt + 1, p ^ 1);
            STAGEV(kt + 1, p ^ 1);
        }
        const unsigned char* Klp = Klb + p * 4096;
        const unsigned char* Vlp = Vlb + p * 5120;

        // S^T = K Q^T (swapped, fp8): lane holds S[q=qblock+q16][k=kf*16+g*4+i].
        f32x4 s[2][2];
        #pragma unroll
        for (int rf = 0; rf < 2; ++rf)
            #pragma unroll
            for (int kf = 0; kf < 2; ++kf)
                s[rf][kf] = (f32x4){0.f, 0.f, 0.f, 0.f};
        __builtin_amdgcn_s_setprio(1);
        #pragma unroll
        for (int ks = 0; ks < 4; ++ks) {
            int sw = (((2 * ks + (g >> 1)) ^ (q16 & 7)) * 16) + ((g & 1) * 8);
            long qv0 = *(const long*)&Ql8[(qw * 32 + q16) * 128 + sw];
            long qv1 = *(const long*)&Ql8[(qw * 32 + 16 + q16) * 128 + sw];
            #pragma unroll
            for (int kf = 0; kf < 2; ++kf) {
                long kv = *(const long*)&Klp[(kf * 16 + q16) * 128 + sw];
                s[0][kf] = __builtin_amdgcn_mfma_f32_16x16x32_fp8_fp8(kv, qv0, s[0][kf], 0, 0, 0);
                s[1][kf] = __builtin_amdgcn_mfma_f32_16x16x32_fp8_fp8(kv, qv1, s[1][kf], 0, 0, 0);
            }
        }
        __builtin_amdgcn_s_setprio(0);

        // no-max softmax: p = exp2(S) (SCALEL pre-folded into Q); pack P to fp8
        long pa8[2];
        #pragma unroll
        for (int rf = 0; rf < 2; ++rf) {
            #pragma unroll
            for (int kf = 0; kf < 2; ++kf)
                #pragma unroll
                for (int i = 0; i < 4; ++i)
                    s[rf][kf][i] = exp2f(s[rf][kf][i]);
            l_loc[rf] += (s[rf][0][0] + s[rf][0][1]) + (s[rf][0][2] + s[rf][0][3])
                       + (s[rf][1][0] + s[rf][1][1]) + (s[rf][1][2] + s[rf][1][3]);
            int2 pk2;
            pk2.x = pk4fp8(s[rf][0][0], s[rf][0][1], s[rf][0][2], s[rf][0][3]);
            pk2.y = pk4fp8(s[rf][1][0], s[rf][1][1], s[rf][1][2], s[rf][1][3]);
            pa8[rf] = __builtin_bit_cast(long, pk2);
        }

        // O += P @ V (fp8). V image row d: lane's 8 byte-slots at g*8 (one b64).
        __builtin_amdgcn_s_setprio(1);
        #pragma unroll
        for (int df = 0; df < 8; ++df) {
            int d = df * 16 + q16;
            long vv = *(const long*)&Vlp[d * 40 + g * 8];
            acc_o[0][df] = __builtin_amdgcn_mfma_f32_16x16x32_fp8_fp8(pa8[0], vv, acc_o[0][df], 0, 0, 0);
            acc_o[1][df] = __builtin_amdgcn_mfma_f32_16x16x32_fp8_fp8(pa8[1], vv, acc_o[1][df], 0, 0, 0);
        }
        __builtin_amdgcn_s_setprio(0);

        __syncthreads();   // drains tile-(kt+1) DMA, fences reuse of buf[p]
    }

    // ---- merge across 8 KV groups ----
    float l0 = l_loc[0], l1 = l_loc[1];
    l0 += __shfl_xor(l0, 16); l0 += __shfl_xor(l0, 32);
    l1 += __shfl_xor(l1, 16); l1 += __shfl_xor(l1, 32);

    float* lf = (float*)smem;                       // [8 grp][64 rows]
    unsigned short* Ub = smem + 8192;               // [8 grp][64][132] bf16 @byte 16384
    if (g == 0) {
        lf[grp * 64 + qw * 32 + q16]      = l0;
        lf[grp * 64 + qw * 32 + 16 + q16] = l1;
    }
    {
        unsigned short* Ug = Ub + grp * 8448;
        #pragma unroll
        for (int rf = 0; rf < 2; ++rf)
            #pragma unroll
            for (int df = 0; df < 8; ++df)
                #pragma unroll
                for (int i = 0; i < 4; ++i)
                    Ug[(qw * 32 + rf * 16 + g * 4 + i) * 132 + df * 16 + q16] =
                        f2bf(acc_o[rf][df][i]);
    }
    __syncthreads();

    // combine: wave wv_ handles q-rows [wv_*4, wv_*4+4), lane covers 2 d-cols
    #pragma unroll
    for (int r = 0; r < 4; ++r) {
        int row = wv_ * 4 + r;
        float lt = 0.f;
        #pragma unroll
        for (int gg = 0; gg < 8; ++gg) lt += lf[gg * 64 + row];
        float inv = 1.f / lt;
        float o0 = 0.f, o1 = 0.f;
        #pragma unroll
        for (int gg = 0; gg < 8; ++gg) {
            unsigned int u = *(const unsigned int*)&Ub[gg * 8448 + row * 132 + lane * 2];
            o0 += __builtin_bit_cast(float, u << 16);
            o1 += __builtin_bit_cast(float, u & 0xffff0000u);
        }
        unsigned int packed = ((unsigned int)f2bf(o1 * inv) << 16) | f2bf(o0 * inv);
        *(unsigned int*)&Ob[((size_t)b * N_ + n0 + row) * RC_ + lane * 2] = packed;
    }
    #undef STAGEK
    #undef STAGEV
}

// ---------------- kernel 3: output projection + residual (NBLK=128) ----------------
#define QS 136  // 128 + 8 pad (shorts)

__global__ __launch_bounds__(256) void k_out(
    const unsigned short* __restrict__ Ob, const float* __restrict__ wo,
    const float* __restrict__ bo, const float* __restrict__ x,
    const float* __restrict__ gamma, float* __restrict__ out)
{
    __shared__ unsigned short Ol[128 * QS];   // 34.8 KB
    const int b  = blockIdx.z;
    const int c0 = blockIdx.y * 64;
    const int n0 = blockIdx.x * 128;
    const int t  = threadIdx.x;
    const int lane = t & 63, wv_ = t >> 6;
    const int g = lane >> 4, q16 = lane & 15;

    {
        const unsigned short* src = Ob + ((size_t)b * N_ + n0) * RC_;
        #pragma unroll
        for (int p = 0; p < 8; ++p) {
            int row = p * 16 + (t >> 4);
            int s = (t & 15) * 8;
            *(u16x8*)&Ol[row * QS + s] = *(const u16x8*)&src[row * RC_ + s];
        }
    }
    __syncthreads();

    f32x4 acc[8];
    #pragma unroll
    for (int nf = 0; nf < 8; ++nf)
        acc[nf] = (f32x4){0.f, 0.f, 0.f, 0.f};

    const int cw = c0 + wv_ * 16;
    #pragma unroll
    for (int ks = 0; ks < 4; ++ks) {
        u16x8 a8 = ldw8(&wo[(size_t)(cw + q16) * 128 + ks * 32 + g * 8]);
        #pragma unroll
        for (int nf = 0; nf < 8; ++nf) {
            u16x8 b8 = *(const u16x8*)&Ol[(nf * 16 + q16) * QS + ks * 32 + g * 8];
            acc[nf] = mfma16(a8, b8, acc[nf]);
        }
    }

    float gm = gamma[0];
    #pragma unroll
    for (int i = 0; i < 4; ++i) {
        int c = cw + g * 4 + i;
        float bias = bo[c];
        #pragma unroll
        for (int nf = 0; nf < 8; ++nf) {
            int n = n0 + nf * 16 + q16;
            size_t idx = ((size_t)b * C_ + c) * N_ + n;
            out[idx] = gm * (acc[nf][i] + bias) + x[idx];
        }
    }
}

extern "C" void kernel_launch(void* const* d_in, const int* in_sizes, int n_in,
                              void* d_out, int out_size, void* d_ws, size_t ws_size,
                              hipStream_t stream) {
    const float* x     = (const float*)d_in[0];
    const float* wq    = (const float*)d_in[1];
    const float* bq    = (const float*)d_in[2];
    const float* wk    = (const float*)d_in[3];
    const float* bk    = (const float*)d_in[4];
    const float* wv    = (const float*)d_in[5];
    const float* bv    = (const float*)d_in[6];
    const float* wo    = (const float*)d_in[7];
    const float* bo    = (const float*)d_in[8];
    const float* gamma = (const float*)d_in[9];
    float* out = (float*)d_out;

    unsigned char* wsb = (unsigned char*)d_ws;
    unsigned char* Qf  = wsb;                               // [B][N][RC] fp8, 2MB
    unsigned char* Kf  = wsb + 2097152;                     // [B][N][RC] fp8, 2MB
    unsigned char* Vt8 = wsb + 4194304;                     // [B*128][128][40]B fp8 image, 2.62MB
    unsigned short* Ob = (unsigned short*)(wsb + 6815744);  // [B][N][RC] bf16, 4MB

    dim3 g1(64, 4);
    k_qkv<<<g1, 256, 0, stream>>>(x, wq, wk, wv, bq, bk, bv, Qf, Kf, Vt8);
    dim3 g2(64, 4);
    k_attn<<<g2, 1024, 0, stream>>>(Qf, Kf, Vt8, Ob);
    dim3 g3(32, 4, 4);
    k_out<<<g3, 256, 0, stream>>>(Ob, wo, bo, x, gamma, out);
}